// Round 6
// baseline (616.651 us; speedup 1.0000x reference)
//
#include <hip/hip_runtime.h>
#include <cstdint>
#include <cstddef>

#define NN   4096
#define LLC  50

__device__ __forceinline__ float bf2f(unsigned short u) {
    return __uint_as_float(((unsigned)u) << 16);
}
__device__ __forceinline__ unsigned short f2bf(float x) {
    unsigned b = __float_as_uint(x);
    return (unsigned short)((b + 0x7fffu + ((b >> 16) & 1u)) >> 16);
}

#if __has_builtin(__builtin_amdgcn_sdot4)
#define SDOT4(a, b, c) __builtin_amdgcn_sdot4((int)(a), (int)(b), (c), false)
#else
__device__ __forceinline__ int sdot4_sw(unsigned a, unsigned b, int c) {
    c += (int)(signed char)(a) * (int)(signed char)(b);
    c += (int)(signed char)(a >> 8) * (int)(signed char)(b >> 8);
    c += (int)(signed char)(a >> 16) * (int)(signed char)(b >> 16);
    c += (int)(signed char)(a >> 24) * (int)(signed char)(b >> 24);
    return c;
}
#define SDOT4(a, b, c) sdot4_sw((a), (b), (c))
#endif

// sum across 64 lanes via DPP (VALU pipe); total lands in lane 63
#define DPPADD(v, ctrl, rmask) \
    ((v) + __builtin_amdgcn_update_dpp(0, (v), (ctrl), (rmask), 0xf, true))
__device__ __forceinline__ int wred64(int v) {
    v = DPPADD(v, 0x111, 0xf);   // row_shr:1
    v = DPPADD(v, 0x112, 0xf);   // row_shr:2
    v = DPPADD(v, 0x114, 0xf);   // row_shr:4
    v = DPPADD(v, 0x118, 0xf);   // row_shr:8
    v = DPPADD(v, 0x142, 0xa);   // row_bcast15
    v = DPPADD(v, 0x143, 0xc);   // row_bcast31 -> lane63=total
    return v;
}

// ---- xproj[p=l*4+b][n] — the ONLY pre-kernel (RNN step 0 needs xp at once) --
__global__ __launch_bounds__(256) void k_xproj(const float* __restrict__ item_emb,
                                               const int* __restrict__ joblst,
                                               const float* __restrict__ W_ih,
                                               const float* __restrict__ b_ih,
                                               const float* __restrict__ b_hh,
                                               float* __restrict__ xp) {
    __shared__ float sx[8][128];
    int t = threadIdx.x;
    int n = blockIdx.x * 256 + t;
    int p0 = blockIdx.y * 8;
#pragma unroll
    for (int i = 0; i < 4; ++i) {
        int e2 = t + i * 256;
        int rr = e2 >> 7, c = e2 & 127;
        int p = p0 + rr;
        int b = p & 3, l = p >> 2;
        int j = joblst[b * LLC + l];
        sx[rr][c] = item_emb[(size_t)j * 128 + c];
    }
    __syncthreads();
    float acc[8];
#pragma unroll
    for (int r = 0; r < 8; ++r) acc[r] = 0.f;
    const float* wn = W_ih + (size_t)n * 128;
    for (int c = 0; c < 128; c += 4) {
        float4 w = *(const float4*)(wn + c);
#pragma unroll
        for (int r = 0; r < 8; ++r) {
            float4 xr = *(const float4*)&sx[r][c];
            acc[r] += xr.x * w.x + xr.y * w.y + xr.z * w.z + xr.w * w.w;
        }
    }
    float bias = b_ih[n] + b_hh[n];
#pragma unroll
    for (int r = 0; r < 8; ++r) xp[(size_t)(p0 + r) * NN + n] = acc[r] + bias;
}

// ---- gather edge accumulation: 2 features/lane, 8-deep pipelined, plain
// (L1/L2-cached) loads. FP accumulation order is strictly edge-sequential.
__device__ __forceinline__ void row_acc(const unsigned* __restrict__ eps, int e0, int e1,
                                        const unsigned* __restrict__ Xd, unsigned bbase,
                                        unsigned lane, float& a0, float& a1) {
    int e = e0;
    for (; e + 8 <= e1; e += 8) {
        unsigned p[8], x[8];
#pragma unroll
        for (int i = 0; i < 8; ++i) p[i] = eps[e + i];
#pragma unroll
        for (int i = 0; i < 8; ++i)
            x[i] = Xd[((size_t)(bbase + (p[i] >> 16)) << 6) + lane];
#pragma unroll
        for (int i = 0; i < 8; ++i) {
            float v = bf2f((unsigned short)p[i]);
            a0 += v * bf2f((unsigned short)x[i]);
            a1 += v * bf2f((unsigned short)(x[i] >> 16));
        }
    }
    for (; e < e1; ++e) {
        unsigned pp = eps[e];
        unsigned xw = Xd[((size_t)(bbase + (pp >> 16)) << 6) + lane];
        float v = bf2f((unsigned short)pp);
        a0 += v * bf2f((unsigned short)xw);
        a1 += v * bf2f((unsigned short)(xw >> 16));
    }
}

// Worker phase barrier (512 blocks): release(wbl2) -> arrive -> spin ->
// acquire(inv). Proven pattern (rounds 2-5) generalized to per-phase counters.
#define WBAR(IDX)                                                              \
    __syncthreads();                                                           \
    if (t == 0) {                                                              \
        __builtin_amdgcn_fence(__ATOMIC_RELEASE, "agent");                     \
        __hip_atomic_fetch_add(&bar[IDX], 1, __ATOMIC_RELAXED,                 \
                               __HIP_MEMORY_SCOPE_AGENT);                      \
        while (__hip_atomic_load(&bar[IDX], __ATOMIC_RELAXED,                  \
                                 __HIP_MEMORY_SCOPE_AGENT) < 512)              \
            __builtin_amdgcn_s_sleep(4);                                       \
        __builtin_amdgcn_fence(__ATOMIC_ACQUIRE, "agent");                     \
    }                                                                          \
    __syncthreads();

// ---- MEGA: RNN (blocks 0..255) || full sparse pipeline (blocks 256..767) ----
// RNN path: byte-identical to round 2 (proven 293us with workers).
// Worker phases (each bit-exact vs the deleted standalone kernels):
//   A: hist   (512 blk x 2048 edges, LDS-privatized -> global atomics)
//   B: scan   (16 blk; prefix -> rowptr/cursor)
//   C: scatter (2048 edges/blk, cursor atomics -> ep) + filt GEMM (32 rows/blk)
//   D: gather1 (y = inv@filt)
//   E: gather2 + fused gelu(res.dW+db) -> g1
// Visibility between phases: device-scope atomics at coherence point
// (counts/cursor) or plain stores + WBAR fences (rowptr/ep/filt/y).
// Residency structural (3 blocks/CU); barriers deadlock-free.
__global__ __launch_bounds__(256, 2) void k_mega(
        const float* __restrict__ W_hh,
        const float* __restrict__ xp,
        unsigned* __restrict__ hq,           // [2][4096]
        float* __restrict__ hfin,
        int* __restrict__ bar,               // [512] ints (zeroed)
        int* __restrict__ rowptr,
        unsigned* __restrict__ ep,
        unsigned short* __restrict__ filt1,
        unsigned short* __restrict__ filt2,
        unsigned short* __restrict__ y1,
        unsigned short* __restrict__ y2,
        const float* __restrict__ dW,
        const float* __restrict__ db,
        float* __restrict__ g1,
        const float* __restrict__ fea,
        const float* __restrict__ W1,
        const float* __restrict__ W2,
        const int* __restrict__ i0, const int* __restrict__ i1,
        const int* __restrict__ i2, const int* __restrict__ i3,
        const float* __restrict__ v0, const float* __restrict__ v1,
        const float* __restrict__ v2, const float* __restrict__ v3,
        const float* __restrict__ dd1, const float* __restrict__ dd2,
        int* __restrict__ counts,
        int* __restrict__ cursor) {
    __shared__ unsigned hs[4352];              // RNN h / hist lc / filt stage / fs
    __shared__ int red[4][16];
    __shared__ unsigned char hpk[4][4][4];     // [wv][b][rr]
    int t = threadIdx.x;
    int lane = t & 63, wv = t >> 6;
    int blk = blockIdx.x;

    if (blk >= 256) {
        int w = blk - 256;                     // 0..511
        int c7 = w & 7;
        // ================= phase A: hist (LDS-privatized) ====================
        {
            int* lc = (int*)hs;
#pragma unroll
            for (int i = 0; i < 16; ++i) lc[t + i * 256] = 0;
            __syncthreads();
            unsigned s = (unsigned)w >> 5, ch = (unsigned)w & 31;
            unsigned m = s >> 2, b = s & 3;
            const int* ip = (m == 0) ? i0 : (m == 1) ? i1 : (m == 2) ? i2 : i3;
            unsigned base = b * 131072u + ch * 2048u;
#pragma unroll
            for (int i = 0; i < 8; ++i) {
                int r = ip[base + t + i * 256];
                atomicAdd(&lc[r], 1);
            }
            __syncthreads();
            int* cs = counts + s * 4096;
#pragma unroll
            for (int i = 0; i < 16; ++i) {
                int v = lc[t + i * 256];
                if (v) atomicAdd(cs + t + i * 256, v);
            }
        }
        WBAR(320)
        // ================= phase B: scan (blocks 0..15 only) =================
        if (w < 16) {
            int s = w;
            int loc[16];
            int base = t * 16;
            const int* cs = counts + s * 4096;
            int run = 0;
#pragma unroll
            for (int i = 0; i < 16; ++i) { loc[i] = run; run += cs[base + i]; }
            int total = run;
            int v = total;
#pragma unroll
            for (int d = 1; d < 64; d <<= 1) { int u = __shfl_up(v, d, 64); if (lane >= d) v += u; }
            if (lane == 63) red[0][wv] = v;
            __syncthreads();
            int pre = v - total;
            for (int i = 0; i < wv; ++i) pre += red[0][i];
            int* rp = rowptr + s * 4097;
            int* cu = cursor + s * 4096;
#pragma unroll
            for (int i = 0; i < 16; ++i) { rp[base + i] = pre + loc[i]; cu[base + i] = pre + loc[i]; }
            if (t == 255) rp[4096] = pre + total;
        }
        WBAR(328)
        // ================= phase C: scatter + filt ===========================
        {   // scatter: per-edge math identical to the old k_scatter
            unsigned s = (unsigned)w >> 5, ch = (unsigned)w & 31;
            unsigned m = s >> 2, b = s & 3;
            const int* ip = (m == 0) ? i0 : (m == 1) ? i1 : (m == 2) ? i2 : i3;
            const float* vp = (m == 0) ? v0 : (m == 1) ? v1 : (m == 2) ? v2 : v3;
            int* cu = cursor + s * 4096;
#pragma unroll
            for (int i = 0; i < 8; ++i) {
                unsigned e = ch * 2048u + i * 256u + t;
                int r = ip[(size_t)b * 131072 + e];
                int c = ip[(size_t)b * 131072 + 65536 + e];
                float v = vp[(size_t)b * 65536 + e];
                if (m == 1) v *= dd1[c];
                if (m == 3) v *= dd2[c];
                int pos = atomicAdd(cu + r, 1);
                ep[(size_t)s * 65536 + pos] = ((unsigned)c << 16) | (unsigned)f2bf(v);
            }
        }
        {   // filt: rows w*32..w*32+31; inner math bit-identical to old k_filt
            int rb = w * 32;
            float* sfea = (float*)hs;          // [32][128] = 16KB
#pragma unroll
            for (int i = 0; i < 16; ++i) {
                int idx = t + i * 256;
                sfea[idx] = fea[(size_t)rb * 128 + idx];
            }
            __syncthreads();
            int half = t >> 7, tc = t & 127;
            const float* sf = sfea + half * (16 * 128);
            float a1[16], a2[16];
#pragma unroll
            for (int r = 0; r < 16; ++r) { a1[r] = 0.f; a2[r] = 0.f; }
            for (int c = 0; c < 128; c += 4) {
                float w10 = W1[(c + 0) * 128 + tc], w11 = W1[(c + 1) * 128 + tc];
                float w12 = W1[(c + 2) * 128 + tc], w13 = W1[(c + 3) * 128 + tc];
                float w20 = W2[(c + 0) * 128 + tc], w21 = W2[(c + 1) * 128 + tc];
                float w22 = W2[(c + 2) * 128 + tc], w23 = W2[(c + 3) * 128 + tc];
#pragma unroll
                for (int r = 0; r < 16; ++r) {
                    float4 f = *(const float4*)&sf[r * 128 + c];
                    a1[r] += f.x * w10 + f.y * w11 + f.z * w12 + f.w * w13;
                    a2[r] += f.x * w20 + f.y * w21 + f.z * w22 + f.w * w23;
                }
            }
#pragma unroll
            for (int r = 0; r < 16; ++r) {
                size_t o = (size_t)(rb + half * 16 + r) * 128 + tc;
                filt1[o] = f2bf(a1[r]);
                filt2[o] = f2bf(a2[r]);
            }
        }
        WBAR(336)
        // ================= phase D: gather1 (y = inv@filt) ===================
        {
            unsigned mm = c7 & 1, b = (unsigned)c7 >> 1;
            int s = (mm ? 8 : 0) + (int)b;
            const unsigned* Xd = (const unsigned*)(mm ? filt2 : filt1);
            unsigned* Yd = (unsigned*)(mm ? y2 : y1);
            const int* rp = rowptr + s * 4097;
            const unsigned* eps = ep + (size_t)s * 65536;
            unsigned bbase = b * 4096;
            int g = w >> 3;                    // 0..63
            int row0 = (g * 4 + wv) * 16;
            for (int rr = 0; rr < 16; ++rr) {
                int row = row0 + rr;
                float a0 = 0.f, a1 = 0.f;
                row_acc(eps, rp[row], rp[row + 1], Xd, bbase, lane, a0, a1);
                Yd[((size_t)(bbase + row) << 6) + lane] =
                    (unsigned)f2bf(a0) | ((unsigned)f2bf(a1) << 16);
            }
        }
        WBAR(344)
        // ================= phase E: gather2 + g1 dot =========================
        {
            unsigned b = (unsigned)c7 >> 1;
            unsigned bbase = b * 4096;
            const int* rpA = rowptr + (4 + (int)b) * 4097;
            const int* rpB = rowptr + (12 + (int)b) * 4097;
            const unsigned* epA = ep + (size_t)(4 + b) * 65536;
            const unsigned* epB = ep + (size_t)(12 + b) * 65536;
            const unsigned* y1d = (const unsigned*)y1;
            const unsigned* y2d = (const unsigned*)y2;
            int g2 = (w >> 3) * 2 + (w & 1);   // 0..127
            int row0 = (g2 * 4 + wv) * 8;
            float* fs = (float*)hs + wv * 1056;        // 8 rows x 132 (padded)
            for (int rr = 0; rr < 8; ++rr) {
                int row = row0 + rr;
                float a0 = 0.f, a1 = 0.f;
                row_acc(epA, rpA[row], rpA[row + 1], y1d, bbase, lane, a0, a1);
                row_acc(epB, rpB[row], rpB[row + 1], y2d, bbase, lane, a0, a1);
                *(float2*)(fs + rr * 132 + 2 * lane) = make_float2(a0, a1);
            }
#pragma unroll
            for (int pass = 0; pass < 2; ++pass) {
                int task = lane + pass * 64;
                if (task < 80) {
                    int rr = task / 10, k = task - rr * 10;
                    const float* rrp = fs + rr * 132;
                    const float4* wk4 = (const float4*)(dW + (size_t)k * 128);
                    float acc = 0.f;
#pragma unroll
                    for (int c4 = 0; c4 < 32; ++c4) {
                        float4 a = *(const float4*)(rrp + c4 * 4);
                        float4 wq = wk4[c4];
                        acc += a.x * wq.x + a.y * wq.y + a.z * wq.z + a.w * wq.w;
                    }
                    float pre = acc + db[k];
                    float gg = 0.5f * pre * (1.f + erff(pre * 0.70710678118f));
                    g1[(size_t)(bbase + row0 + rr) * 10 + k] = gg;
                }
            }
        }
        return;
    }

    // ========================== RNN PATH (blocks 0..255) =====================
    // (byte-identical to round 2's RNN path)
    int row_base = ((blk & 7) * 32 + (blk >> 3)) * 16;   // XCD-sliced: 512 rows/XCD
    int wrow = row_base + wv * 4;

    uint4 W[4][4];
    {
        const float* wsrc = W_hh + (size_t)wrow * 4096;
#pragma unroll
        for (int r = 0; r < 4; ++r)
#pragma unroll
            for (int k4 = 0; k4 < 4; ++k4) {
                unsigned q[4];
#pragma unroll
                for (int i = 0; i < 4; ++i) {
                    const float* p = wsrc + (size_t)r * 4096 + (lane * 16 + k4 * 4 + i) * 4;
                    float4 w = *(const float4*)p;
                    int q0 = (int)rintf(fminf(fmaxf(w.x * 8192.f, -127.f), 127.f));
                    int q1 = (int)rintf(fminf(fmaxf(w.y * 8192.f, -127.f), 127.f));
                    int q2 = (int)rintf(fminf(fmaxf(w.z * 8192.f, -127.f), 127.f));
                    int q3 = (int)rintf(fminf(fmaxf(w.w * 8192.f, -127.f), 127.f));
                    q[i] = (q0 & 0xff) | ((q1 & 0xff) << 8) | ((q2 & 0xff) << 16) | ((q3 & 0xff) << 24);
                }
                W[r][k4] = make_uint4(q[0], q[1], q[2], q[3]);
            }
    }

    const float SC = 1.f / (8192.f * 127.f);

    for (int l = 0; l < LLC; ++l) {
        if (l > 0) {
            const unsigned* src = hq + (size_t)((l - 1) & 1) * 4096;
            unsigned sval[16];
#pragma unroll
            for (int k = 0; k < 16; ++k)
                sval[k] = __hip_atomic_load(src + t + k * 256, __ATOMIC_RELAXED,
                                            __HIP_MEMORY_SCOPE_AGENT);
#pragma unroll
            for (int k = 0; k < 16; ++k) hs[t + k * 256] = sval[k];
            __syncthreads();

            __builtin_amdgcn_s_setprio(1);
            uint4 H[4][4];
#pragma unroll
            for (int b = 0; b < 4; ++b)
#pragma unroll
                for (int k4 = 0; k4 < 4; ++k4)
                    H[b][k4] = ((const uint4*)hs)[k4 * 256 + b * 64 + lane];
            int acc[4][4];
#pragma unroll
            for (int r = 0; r < 4; ++r)
#pragma unroll
                for (int b = 0; b < 4; ++b) acc[r][b] = 0;
#pragma unroll
            for (int k4 = 0; k4 < 4; ++k4)
#pragma unroll
                for (int r = 0; r < 4; ++r)
#pragma unroll
                    for (int b = 0; b < 4; ++b) {
                        acc[r][b] = SDOT4(W[r][k4].x, H[b][k4].x, acc[r][b]);
                        acc[r][b] = SDOT4(W[r][k4].y, H[b][k4].y, acc[r][b]);
                        acc[r][b] = SDOT4(W[r][k4].z, H[b][k4].z, acc[r][b]);
                        acc[r][b] = SDOT4(W[r][k4].w, H[b][k4].w, acc[r][b]);
                    }
#pragma unroll
            for (int r = 0; r < 4; ++r)
#pragma unroll
                for (int b = 0; b < 4; ++b) acc[r][b] = wred64(acc[r][b]);
            if (lane == 63) {
#pragma unroll
                for (int b = 0; b < 4; ++b) {
                    int4 q = { acc[0][b], acc[1][b], acc[2][b], acc[3][b] };
                    *(int4*)&red[wv][b * 4] = q;
                }
            }
            __builtin_amdgcn_s_setprio(0);
        }
        if (lane < 16) {
            int b = lane >> 2, rr = lane & 3;
            int row = wrow + rr;
            float a = (l > 0) ? (float)red[wv][lane] * SC : 0.f;
            float pre = a + xp[(size_t)(l * 4 + b) * NN + row];
            float hnew = tanhf(pre);
            if (l == LLC - 1) hfin[(size_t)b * NN + row] = hnew;
            int q = (int)rintf(hnew * 127.f);
            hpk[wv][b][rr] = (unsigned char)(q & 0xff);
        }
        if (l < LLC - 1) {
            if (lane < 4) {
                int b = lane;
                unsigned d = *(const unsigned*)&hpk[wv][b][0];
                int hk = (row_base >> 2) + wv;
                int phys = ((hk >> 2) & 3) * 1024 + b * 256 + (hk >> 4) * 4 + (hk & 3);
                __hip_atomic_store(hq + (size_t)(l & 1) * 4096 + phys, d,
                                   __ATOMIC_RELAXED, __HIP_MEMORY_SCOPE_AGENT);
            }
            __syncthreads();
            if (t == 0) {
                int g = blk & 7;
                int old = __hip_atomic_fetch_add(&bar[g * 32], 1, __ATOMIC_RELAXED,
                                                 __HIP_MEMORY_SCOPE_AGENT);
                if ((old & 31) == 31)
                    __hip_atomic_fetch_add(&bar[256], 1, __ATOMIC_RELAXED,
                                           __HIP_MEMORY_SCOPE_AGENT);
                int target = 8 * (l + 1);
                while (__hip_atomic_load(&bar[256], __ATOMIC_RELAXED,
                                         __HIP_MEMORY_SCOPE_AGENT) < target)
                    __builtin_amdgcn_s_sleep(2);
            }
            __syncthreads();
        }
    }
}

// ---- out = sigmoid( g1 * gelu(hfin) ), elementwise -------------------------
__global__ __launch_bounds__(256) void k_out(const float* __restrict__ g1,
                                             const float* __restrict__ hfin,
                                             float* __restrict__ out) {
    int i = blockIdx.x * 256 + threadIdx.x;        // [0, 163840)
    int grow = i / 10;
    float e = hfin[grow];
    float ge = 0.5f * e * (1.f + erff(e * 0.70710678118f));
    out[i] = 1.f / (1.f + __expf(-g1[i] * ge));
}

extern "C" void kernel_launch(void* const* d_in, const int* in_sizes, int n_in,
                              void* d_out, int out_size, void* d_ws, size_t ws_size,
                              hipStream_t stream) {
    const int*   phi1_idx = (const int*)d_in[0];
    const float* phi1_val = (const float*)d_in[1];
    const int*   inv1_idx = (const int*)d_in[2];
    const float* inv1_val = (const float*)d_in[3];
    const int*   phi2_idx = (const int*)d_in[4];
    const float* phi2_val = (const float*)d_in[5];
    const int*   inv2_idx = (const int*)d_in[6];
    const float* inv2_val = (const float*)d_in[7];
    const float* fea      = (const float*)d_in[8];
    const int*   joblst   = (const int*)d_in[9];
    const float* W1       = (const float*)d_in[10];
    const float* d1       = (const float*)d_in[11];
    const float* W2       = (const float*)d_in[12];
    const float* d2       = (const float*)d_in[13];
    const float* W_ih     = (const float*)d_in[14];
    const float* W_hh     = (const float*)d_in[15];
    const float* b_ih     = (const float*)d_in[16];
    const float* b_hh     = (const float*)d_in[17];
    const float* dense_W  = (const float*)d_in[18];
    const float* dense_b  = (const float*)d_in[19];
    const float* item_emb = (const float*)d_in[20];

    float* ws = (float*)d_ws;                       // slot = 4B
    unsigned short* filt1 = (unsigned short*)ws;            // 1,048,576 slots
    unsigned short* filt2 = (unsigned short*)(ws + 1048576);
    unsigned short* y1    = (unsigned short*)(ws + 2097152);
    unsigned short* y2    = (unsigned short*)(ws + 3145728);
    float* g1   = ws + 4194304;                     // 163,840 slots
    float* xp   = ws + 6291456;                     // 819,200
    float* hfin = ws + 7110656;                     // 16,384
    unsigned* hq  = (unsigned*)(ws + 7127040);      // 8,192 (2 x 4096 dwords)
    int*   counts = (int*)(ws + 11329536);          // 65,536
    int*   rowptr = (int*)(ws + 11395072);          // 65,552
    int*   cursor = (int*)(ws + 11460624);          // 65,536
    unsigned* ep  = (unsigned*)(ws + 11526160);     // 1,048,576 (packed col|val)
    int*   bar    = (int*)(ws + 12574736);          // 512 ints (RNN + worker phases)

    hipMemsetAsync(counts, 0, 16 * 4096 * sizeof(int), stream);
    hipMemsetAsync(bar, 0, 2048, stream);

    k_xproj<<<dim3(16, 25), 256, 0, stream>>>(item_emb, joblst, W_ih, b_ih, b_hh, xp);

    // Everything else lives inside k_mega: RNN on blocks 0..255; the whole
    // sparse pipeline (hist/scan/scatter/filt/gather1/gather2+g1) on 256..767.
    k_mega<<<768, 256, 0, stream>>>(W_hh, xp, hq, hfin, bar,
                                    rowptr, ep, filt1, filt2, y1, y2,
                                    dense_W, dense_b, g1,
                                    fea, W1, W2,
                                    inv1_idx, phi1_idx, inv2_idx, phi2_idx,
                                    inv1_val, phi1_val, inv2_val, phi2_val,
                                    d1, d2, counts, cursor);

    k_out<<<640, 256, 0, stream>>>(g1, hfin, (float*)d_out);
}

// Round 7
// 588.303 us; speedup vs baseline: 1.0482x; 1.0482x over previous
//
#include <hip/hip_runtime.h>
#include <cstdint>
#include <cstddef>

#define NN   4096
#define LLC  50

__device__ __forceinline__ float bf2f(unsigned short u) {
    return __uint_as_float(((unsigned)u) << 16);
}
__device__ __forceinline__ unsigned short f2bf(float x) {
    unsigned b = __float_as_uint(x);
    return (unsigned short)((b + 0x7fffu + ((b >> 16) & 1u)) >> 16);
}

#if __has_builtin(__builtin_amdgcn_sdot4)
#define SDOT4(a, b, c) __builtin_amdgcn_sdot4((int)(a), (int)(b), (c), false)
#else
__device__ __forceinline__ int sdot4_sw(unsigned a, unsigned b, int c) {
    c += (int)(signed char)(a) * (int)(signed char)(b);
    c += (int)(signed char)(a >> 8) * (int)(signed char)(b >> 8);
    c += (int)(signed char)(a >> 16) * (int)(signed char)(b >> 16);
    c += (int)(signed char)(a >> 24) * (int)(signed char)(b >> 24);
    return c;
}
#define SDOT4(a, b, c) sdot4_sw((a), (b), (c))
#endif

// sum across 64 lanes via DPP (VALU pipe); total lands in lane 63
#define DPPADD(v, ctrl, rmask) \
    ((v) + __builtin_amdgcn_update_dpp(0, (v), (ctrl), (rmask), 0xf, true))
__device__ __forceinline__ int wred64(int v) {
    v = DPPADD(v, 0x111, 0xf);   // row_shr:1
    v = DPPADD(v, 0x112, 0xf);   // row_shr:2
    v = DPPADD(v, 0x114, 0xf);   // row_shr:4
    v = DPPADD(v, 0x118, 0xf);   // row_shr:8
    v = DPPADD(v, 0x142, 0xa);   // row_bcast15
    v = DPPADD(v, 0x143, 0xc);   // row_bcast31 -> lane63=total
    return v;
}

// Phase barrier for the 512-block prep kernel: release(wbl2) -> arrive ->
// spin -> acquire(inv). Field-proven pattern (rounds 2-6, absmax 0).
#define PBAR(IDX)                                                              \
    __syncthreads();                                                           \
    if (t == 0) {                                                              \
        __builtin_amdgcn_fence(__ATOMIC_RELEASE, "agent");                     \
        __hip_atomic_fetch_add(&bar[IDX], 1, __ATOMIC_RELAXED,                 \
                               __HIP_MEMORY_SCOPE_AGENT);                      \
        while (__hip_atomic_load(&bar[IDX], __ATOMIC_RELAXED,                  \
                                 __HIP_MEMORY_SCOPE_AGENT) < 512)              \
            __builtin_amdgcn_s_sleep(4);                                       \
        __builtin_amdgcn_fence(__ATOMIC_ACQUIRE, "agent");                     \
    }                                                                          \
    __syncthreads();

// ---- PREP: zero+hist+scan+scatter || filt || xproj, one kernel --------------
// 512 blocks x 256 threads; internal phase barriers (co-residency structural:
// 16.4KB LDS, <=96 VGPR => >=6 blocks/CU capacity). All atomic-heavy CSR work
// runs HERE, serially before k_mega, so it cannot contend with the RNN
// (round-6 lesson). Per-element math bit-exact vs the old standalone kernels.
// Phases:
//   P0: zero counts                        (512 blk)
//   P1: hist  (LDS-privatized -> atomics)  (512 blk x 2048 edges)
//   P2: scan  -> rowptr/cursor             (blk 0..15)
//   P3: scatter (blk 0..127) || filt (blk 128..383) || xproj (blk 384..511)
__global__ __launch_bounds__(256, 2) void k_prep(
        const int* __restrict__ i0, const int* __restrict__ i1,
        const int* __restrict__ i2, const int* __restrict__ i3,
        const float* __restrict__ v0, const float* __restrict__ v1,
        const float* __restrict__ v2, const float* __restrict__ v3,
        const float* __restrict__ dd1, const float* __restrict__ dd2,
        const float* __restrict__ fea,
        const float* __restrict__ W1, const float* __restrict__ W2,
        const float* __restrict__ item_emb, const int* __restrict__ joblst,
        const float* __restrict__ W_ih,
        const float* __restrict__ b_ih, const float* __restrict__ b_hh,
        int* __restrict__ counts, int* __restrict__ rowptr,
        int* __restrict__ cursor, unsigned* __restrict__ ep,
        unsigned short* __restrict__ filt1, unsigned short* __restrict__ filt2,
        float* __restrict__ xp, int* __restrict__ bar) {
    __shared__ float smem[4096];               // 16KB: hist lc / filt stage / xproj sx
    __shared__ int wt4[4];
    int t = threadIdx.x;
    int lane = t & 63, wv = t >> 6;
    int w = blockIdx.x;

    // ---------------- P0: zero counts (65536 ints over 512 blocks) ----------
    if (t < 128) counts[w * 128 + t] = 0;
    PBAR(352)
    // ---------------- P1: hist (round-6-exact) ------------------------------
    {
        int* lc = (int*)smem;
#pragma unroll
        for (int i = 0; i < 16; ++i) lc[t + i * 256] = 0;
        __syncthreads();
        unsigned s = (unsigned)w >> 5, ch = (unsigned)w & 31;
        unsigned m = s >> 2, b = s & 3;
        const int* ip = (m == 0) ? i0 : (m == 1) ? i1 : (m == 2) ? i2 : i3;
        unsigned base = b * 131072u + ch * 2048u;
#pragma unroll
        for (int i = 0; i < 8; ++i) {
            int r = ip[base + t + i * 256];
            atomicAdd(&lc[r], 1);
        }
        __syncthreads();
        int* cs = counts + s * 4096;
#pragma unroll
        for (int i = 0; i < 16; ++i) {
            int v = lc[t + i * 256];
            if (v) atomicAdd(cs + t + i * 256, v);
        }
    }
    PBAR(360)
    // ---------------- P2: scan (blocks 0..15, round-6-exact) ----------------
    if (w < 16) {
        int s = w;
        int loc[16];
        int base = t * 16;
        const int* cs = counts + s * 4096;
        int run = 0;
#pragma unroll
        for (int i = 0; i < 16; ++i) { loc[i] = run; run += cs[base + i]; }
        int total = run;
        int v = total;
#pragma unroll
        for (int d = 1; d < 64; d <<= 1) { int u = __shfl_up(v, d, 64); if (lane >= d) v += u; }
        if (lane == 63) wt4[wv] = v;
        __syncthreads();
        int pre = v - total;
        for (int i = 0; i < wv; ++i) pre += wt4[i];
        int* rp = rowptr + s * 4097;
        int* cu = cursor + s * 4096;
#pragma unroll
        for (int i = 0; i < 16; ++i) { rp[base + i] = pre + loc[i]; cu[base + i] = pre + loc[i]; }
        if (t == 255) rp[4096] = pre + total;
    }
    PBAR(368)
    // ---------------- P3: scatter || filt || xproj --------------------------
    if (w < 128) {
        // scatter: s = w>>3, 8192 edges/block; per-edge math == old k_scatter
        unsigned s = (unsigned)w >> 3, ch = (unsigned)w & 7;
        unsigned m = s >> 2, b = s & 3;
        const int* ip = (m == 0) ? i0 : (m == 1) ? i1 : (m == 2) ? i2 : i3;
        const float* vp = (m == 0) ? v0 : (m == 1) ? v1 : (m == 2) ? v2 : v3;
        int* cu = cursor + s * 4096;
#pragma unroll 8
        for (int i = 0; i < 32; ++i) {
            unsigned e = ch * 8192u + i * 256u + t;
            int r = ip[(size_t)b * 131072 + e];
            int c = ip[(size_t)b * 131072 + 65536 + e];
            float v = vp[(size_t)b * 65536 + e];
            if (m == 1) v *= dd1[c];
            if (m == 3) v *= dd2[c];
            int pos = atomicAdd(cu + r, 1);
            ep[(size_t)s * 65536 + pos] = ((unsigned)c << 16) | (unsigned)f2bf(v);
        }
    } else if (w < 384) {
        // filt: 64 rows/block in two 32-row stages; inner math == old k_filt
        int rb = (w - 128) * 64;
        for (int st = 0; st < 2; ++st) {
            int rbase = rb + st * 32;
            if (st) __syncthreads();           // prior stage's reads done
#pragma unroll
            for (int i = 0; i < 16; ++i) {
                int idx = t + i * 256;
                smem[idx] = fea[(size_t)rbase * 128 + idx];
            }
            __syncthreads();
            int half = t >> 7, tc = t & 127;
            const float* sf = smem + half * 2048;   // 16 rows x 128
            float a1[16], a2[16];
#pragma unroll
            for (int r = 0; r < 16; ++r) { a1[r] = 0.f; a2[r] = 0.f; }
            for (int c = 0; c < 128; c += 4) {
                float w10 = W1[(c + 0) * 128 + tc], w11 = W1[(c + 1) * 128 + tc];
                float w12 = W1[(c + 2) * 128 + tc], w13 = W1[(c + 3) * 128 + tc];
                float w20 = W2[(c + 0) * 128 + tc], w21 = W2[(c + 1) * 128 + tc];
                float w22 = W2[(c + 2) * 128 + tc], w23 = W2[(c + 3) * 128 + tc];
#pragma unroll
                for (int r = 0; r < 16; ++r) {
                    float4 f = *(const float4*)&sf[r * 128 + c];
                    a1[r] += f.x * w10 + f.y * w11 + f.z * w12 + f.w * w13;
                    a2[r] += f.x * w20 + f.y * w21 + f.z * w22 + f.w * w23;
                }
            }
#pragma unroll
            for (int r = 0; r < 16; ++r) {
                size_t o = (size_t)(rbase + half * 16 + r) * 128 + tc;
                filt1[o] = f2bf(a1[r]);
                filt2[o] = f2bf(a2[r]);
            }
        }
    } else {
        // xproj: 128 blocks; (n-chunk 256) x (p-chunk 25); math == old k_xproj
        int wx = w - 384;
        int nb = wx & 15, pb = wx >> 4;        // pb 0..7
        int p0 = pb * 25;
        for (int idx = t; idx < 25 * 128; idx += 256) {
            int rr = idx >> 7, c = idx & 127;
            int p = p0 + rr;
            int b = p & 3, l = p >> 2;
            int j = joblst[b * LLC + l];
            smem[idx] = item_emb[(size_t)j * 128 + c];
        }
        __syncthreads();
        int n = nb * 256 + t;
        float acc[25];
#pragma unroll
        for (int r = 0; r < 25; ++r) acc[r] = 0.f;
        const float* wn = W_ih + (size_t)n * 128;
        for (int c = 0; c < 128; c += 4) {
            float4 wq = *(const float4*)(wn + c);
#pragma unroll
            for (int r = 0; r < 25; ++r) {
                float4 xr = *(const float4*)&smem[r * 128 + c];
                acc[r] += xr.x * wq.x + xr.y * wq.y + xr.z * wq.z + xr.w * wq.w;
            }
        }
        float bias = b_ih[n] + b_hh[n];
#pragma unroll
        for (int r = 0; r < 25; ++r) xp[(size_t)(p0 + r) * NN + n] = acc[r] + bias;
    }
}

// ---- gather edge accumulation: 2 features/lane, 8-deep pipelined, plain
// (L1/L2-cached) loads. FP accumulation order is strictly edge-sequential.
__device__ __forceinline__ void row_acc(const unsigned* __restrict__ eps, int e0, int e1,
                                        const unsigned* __restrict__ Xd, unsigned bbase,
                                        unsigned lane, float& a0, float& a1) {
    int e = e0;
    for (; e + 8 <= e1; e += 8) {
        unsigned p[8], x[8];
#pragma unroll
        for (int i = 0; i < 8; ++i) p[i] = eps[e + i];
#pragma unroll
        for (int i = 0; i < 8; ++i)
            x[i] = Xd[((size_t)(bbase + (p[i] >> 16)) << 6) + lane];
#pragma unroll
        for (int i = 0; i < 8; ++i) {
            float v = bf2f((unsigned short)p[i]);
            a0 += v * bf2f((unsigned short)x[i]);
            a1 += v * bf2f((unsigned short)(x[i] >> 16));
        }
    }
    for (; e < e1; ++e) {
        unsigned pp = eps[e];
        unsigned xw = Xd[((size_t)(bbase + (pp >> 16)) << 6) + lane];
        float v = bf2f((unsigned short)pp);
        a0 += v * bf2f((unsigned short)xw);
        a1 += v * bf2f((unsigned short)(xw >> 16));
    }
}

// ---- MEGA: RNN (blocks 0..255) || sparse gathers (blocks 256..767) ----------
// ROUND-5 EXACT (proven 293us): RNN path byte-identical to round 2; workers
// do only gather1 / gather2+g1 (atomic-free, L2-cached, one fence barrier).
__global__ __launch_bounds__(256, 2) void k_mega(
        const float* __restrict__ W_hh,
        const float* __restrict__ xp,
        unsigned* __restrict__ hq,           // [2][4096]
        float* __restrict__ hfin,
        int* __restrict__ bar,               // [512] ints (zeroed)
        const int* __restrict__ rowptr,
        const unsigned* __restrict__ ep,
        const unsigned short* __restrict__ filt1,
        const unsigned short* __restrict__ filt2,
        unsigned short* __restrict__ y1,
        unsigned short* __restrict__ y2,
        const float* __restrict__ dW,
        const float* __restrict__ db,
        float* __restrict__ g1) {
    __shared__ unsigned hs[4352];              // RNN: 4096 dwords h; workers: 4x1056 fp row-stage
    __shared__ int red[4][16];
    __shared__ unsigned char hpk[4][4][4];     // [wv][b][rr]
    int t = threadIdx.x;
    int lane = t & 63, wv = t >> 6;
    int blk = blockIdx.x;

    if (blk >= 256) {
        // ================== WORKER PATH: gather1 then gather2+dot ==============
        int w = blk - 256;                     // 0..511; blk%8 == w%8 (XCD heuristic)
        int c7 = w & 7;
        // ---- phase 1: y = inv@filt; combo (mm,b) pinned per XCD residue ----
        {
            unsigned mm = c7 & 1, b = (unsigned)c7 >> 1;
            int s = (mm ? 8 : 0) + (int)b;
            const unsigned* Xd = (const unsigned*)(mm ? filt2 : filt1);
            unsigned* Yd = (unsigned*)(mm ? y2 : y1);
            const int* rp = rowptr + s * 4097;
            const unsigned* eps = ep + (size_t)s * 65536;
            unsigned bbase = b * 4096;
            int g = w >> 3;                    // 0..63
            int row0 = (g * 4 + wv) * 16;
            for (int rr = 0; rr < 16; ++rr) {
                int row = row0 + rr;
                float a0 = 0.f, a1 = 0.f;
                row_acc(eps, rp[row], rp[row + 1], Xd, bbase, lane, a0, a1);
                Yd[((size_t)(bbase + row) << 6) + lane] =
                    (unsigned)f2bf(a0) | ((unsigned)f2bf(a1) << 16);
            }
        }
        // ---- worker phase barrier with cross-XCD fences (per-block) ----
        __syncthreads();                       // vmcnt(0): y stores are in L2
        if (t == 0) {
            __builtin_amdgcn_fence(__ATOMIC_RELEASE, "agent");   // wbl2 -> L3
            __hip_atomic_fetch_add(&bar[320], 1, __ATOMIC_RELAXED,
                                   __HIP_MEMORY_SCOPE_AGENT);
            while (__hip_atomic_load(&bar[320], __ATOMIC_RELAXED,
                                     __HIP_MEMORY_SCOPE_AGENT) < 512)
                __builtin_amdgcn_s_sleep(4);
            __builtin_amdgcn_fence(__ATOMIC_ACQUIRE, "agent");   // inv stale L1/L2
        }
        __syncthreads();
        // ---- phase 2: rows of phi1@y1 + phi2@y2 -> gelu(row.dW[k]+db[k]) ----
        {
            unsigned b = (unsigned)c7 >> 1;
            unsigned bbase = b * 4096;
            const int* rpA = rowptr + (4 + (int)b) * 4097;
            const int* rpB = rowptr + (12 + (int)b) * 4097;
            const unsigned* epA = ep + (size_t)(4 + b) * 65536;
            const unsigned* epB = ep + (size_t)(12 + b) * 65536;
            const unsigned* y1d = (const unsigned*)y1;
            const unsigned* y2d = (const unsigned*)y2;
            int g2 = (w >> 3) * 2 + (w & 1);   // 0..127
            int row0 = (g2 * 4 + wv) * 8;
            float* fs = (float*)hs + wv * 1056;        // 8 rows x 132 (padded)
            for (int rr = 0; rr < 8; ++rr) {
                int row = row0 + rr;
                float a0 = 0.f, a1 = 0.f;
                row_acc(epA, rpA[row], rpA[row + 1], y1d, bbase, lane, a0, a1);
                row_acc(epB, rpB[row], rpB[row + 1], y2d, bbase, lane, a0, a1);
                *(float2*)(fs + rr * 132 + 2 * lane) = make_float2(a0, a1);
            }
#pragma unroll
            for (int pass = 0; pass < 2; ++pass) {
                int task = lane + pass * 64;
                if (task < 80) {
                    int rr = task / 10, k = task - rr * 10;
                    const float* rrp = fs + rr * 132;
                    const float4* wk4 = (const float4*)(dW + (size_t)k * 128);
                    float acc = 0.f;
#pragma unroll
                    for (int c4 = 0; c4 < 32; ++c4) {
                        float4 a = *(const float4*)(rrp + c4 * 4);
                        float4 wq = wk4[c4];
                        acc += a.x * wq.x + a.y * wq.y + a.z * wq.z + a.w * wq.w;
                    }
                    float pre = acc + db[k];
                    float gg = 0.5f * pre * (1.f + erff(pre * 0.70710678118f));
                    g1[(size_t)(bbase + row0 + rr) * 10 + k] = gg;
                }
            }
        }
        return;
    }

    // ========================== RNN PATH (blocks 0..255) =====================
    // (byte-identical to round 2's RNN path)
    int row_base = ((blk & 7) * 32 + (blk >> 3)) * 16;   // XCD-sliced: 512 rows/XCD
    int wrow = row_base + wv * 4;

    uint4 W[4][4];
    {
        const float* wsrc = W_hh + (size_t)wrow * 4096;
#pragma unroll
        for (int r = 0; r < 4; ++r)
#pragma unroll
            for (int k4 = 0; k4 < 4; ++k4) {
                unsigned q[4];
#pragma unroll
                for (int i = 0; i < 4; ++i) {
                    const float* p = wsrc + (size_t)r * 4096 + (lane * 16 + k4 * 4 + i) * 4;
                    float4 w = *(const float4*)p;
                    int q0 = (int)rintf(fminf(fmaxf(w.x * 8192.f, -127.f), 127.f));
                    int q1 = (int)rintf(fminf(fmaxf(w.y * 8192.f, -127.f), 127.f));
                    int q2 = (int)rintf(fminf(fmaxf(w.z * 8192.f, -127.f), 127.f));
                    int q3 = (int)rintf(fminf(fmaxf(w.w * 8192.f, -127.f), 127.f));
                    q[i] = (q0 & 0xff) | ((q1 & 0xff) << 8) | ((q2 & 0xff) << 16) | ((q3 & 0xff) << 24);
                }
                W[r][k4] = make_uint4(q[0], q[1], q[2], q[3]);
            }
    }

    const float SC = 1.f / (8192.f * 127.f);

    for (int l = 0; l < LLC; ++l) {
        if (l > 0) {
            const unsigned* src = hq + (size_t)((l - 1) & 1) * 4096;
            unsigned sval[16];
#pragma unroll
            for (int k = 0; k < 16; ++k)
                sval[k] = __hip_atomic_load(src + t + k * 256, __ATOMIC_RELAXED,
                                            __HIP_MEMORY_SCOPE_AGENT);
#pragma unroll
            for (int k = 0; k < 16; ++k) hs[t + k * 256] = sval[k];
            __syncthreads();

            __builtin_amdgcn_s_setprio(1);
            uint4 H[4][4];
#pragma unroll
            for (int b = 0; b < 4; ++b)
#pragma unroll
                for (int k4 = 0; k4 < 4; ++k4)
                    H[b][k4] = ((const uint4*)hs)[k4 * 256 + b * 64 + lane];
            int acc[4][4];
#pragma unroll
            for (int r = 0; r < 4; ++r)
#pragma unroll
                for (int b = 0; b < 4; ++b) acc[r][b] = 0;
#pragma unroll
            for (int k4 = 0; k4 < 4; ++k4)
#pragma unroll
                for (int r = 0; r < 4; ++r)
#pragma unroll
                    for (int b = 0; b < 4; ++b) {
                        acc[r][b] = SDOT4(W[r][k4].x, H[b][k4].x, acc[r][b]);
                        acc[r][b] = SDOT4(W[r][k4].y, H[b][k4].y, acc[r][b]);
                        acc[r][b] = SDOT4(W[r][k4].z, H[b][k4].z, acc[r][b]);
                        acc[r][b] = SDOT4(W[r][k4].w, H[b][k4].w, acc[r][b]);
                    }
#pragma unroll
            for (int r = 0; r < 4; ++r)
#pragma unroll
                for (int b = 0; b < 4; ++b) acc[r][b] = wred64(acc[r][b]);
            if (lane == 63) {
#pragma unroll
                for (int b = 0; b < 4; ++b) {
                    int4 q = { acc[0][b], acc[1][b], acc[2][b], acc[3][b] };
                    *(int4*)&red[wv][b * 4] = q;
                }
            }
            __builtin_amdgcn_s_setprio(0);
        }
        if (lane < 16) {
            int b = lane >> 2, rr = lane & 3;
            int row = wrow + rr;
            float a = (l > 0) ? (float)red[wv][lane] * SC : 0.f;
            float pre = a + xp[(size_t)(l * 4 + b) * NN + row];
            float hnew = tanhf(pre);
            if (l == LLC - 1) hfin[(size_t)b * NN + row] = hnew;
            int q = (int)rintf(hnew * 127.f);
            hpk[wv][b][rr] = (unsigned char)(q & 0xff);
        }
        if (l < LLC - 1) {
            if (lane < 4) {
                int b = lane;
                unsigned d = *(const unsigned*)&hpk[wv][b][0];
                int hk = (row_base >> 2) + wv;
                int phys = ((hk >> 2) & 3) * 1024 + b * 256 + (hk >> 4) * 4 + (hk & 3);
                __hip_atomic_store(hq + (size_t)(l & 1) * 4096 + phys, d,
                                   __ATOMIC_RELAXED, __HIP_MEMORY_SCOPE_AGENT);
            }
            __syncthreads();
            if (t == 0) {
                int g = blk & 7;
                int old = __hip_atomic_fetch_add(&bar[g * 32], 1, __ATOMIC_RELAXED,
                                                 __HIP_MEMORY_SCOPE_AGENT);
                if ((old & 31) == 31)
                    __hip_atomic_fetch_add(&bar[256], 1, __ATOMIC_RELAXED,
                                           __HIP_MEMORY_SCOPE_AGENT);
                int target = 8 * (l + 1);
                while (__hip_atomic_load(&bar[256], __ATOMIC_RELAXED,
                                         __HIP_MEMORY_SCOPE_AGENT) < target)
                    __builtin_amdgcn_s_sleep(2);
            }
            __syncthreads();
        }
    }
}

// ---- out = sigmoid( g1 * gelu(hfin) ), elementwise -------------------------
__global__ __launch_bounds__(256) void k_out(const float* __restrict__ g1,
                                             const float* __restrict__ hfin,
                                             float* __restrict__ out) {
    int i = blockIdx.x * 256 + threadIdx.x;        // [0, 163840)
    int grow = i / 10;
    float e = hfin[grow];
    float ge = 0.5f * e * (1.f + erff(e * 0.70710678118f));
    out[i] = 1.f / (1.f + __expf(-g1[i] * ge));
}

extern "C" void kernel_launch(void* const* d_in, const int* in_sizes, int n_in,
                              void* d_out, int out_size, void* d_ws, size_t ws_size,
                              hipStream_t stream) {
    const int*   phi1_idx = (const int*)d_in[0];
    const float* phi1_val = (const float*)d_in[1];
    const int*   inv1_idx = (const int*)d_in[2];
    const float* inv1_val = (const float*)d_in[3];
    const int*   phi2_idx = (const int*)d_in[4];
    const float* phi2_val = (const float*)d_in[5];
    const int*   inv2_idx = (const int*)d_in[6];
    const float* inv2_val = (const float*)d_in[7];
    const float* fea      = (const float*)d_in[8];
    const int*   joblst   = (const int*)d_in[9];
    const float* W1       = (const float*)d_in[10];
    const float* d1       = (const float*)d_in[11];
    const float* W2       = (const float*)d_in[12];
    const float* d2       = (const float*)d_in[13];
    const float* W_ih     = (const float*)d_in[14];
    const float* W_hh     = (const float*)d_in[15];
    const float* b_ih     = (const float*)d_in[16];
    const float* b_hh     = (const float*)d_in[17];
    const float* dense_W  = (const float*)d_in[18];
    const float* dense_b  = (const float*)d_in[19];
    const float* item_emb = (const float*)d_in[20];

    float* ws = (float*)d_ws;                       // slot = 4B
    unsigned short* filt1 = (unsigned short*)ws;            // 1,048,576 slots
    unsigned short* filt2 = (unsigned short*)(ws + 1048576);
    unsigned short* y1    = (unsigned short*)(ws + 2097152);
    unsigned short* y2    = (unsigned short*)(ws + 3145728);
    float* g1   = ws + 4194304;                     // 163,840 slots
    float* xp   = ws + 6291456;                     // 819,200
    float* hfin = ws + 7110656;                     // 16,384
    unsigned* hq  = (unsigned*)(ws + 7127040);      // 8,192 (2 x 4096 dwords)
    int*   counts = (int*)(ws + 11329536);          // 65,536
    int*   rowptr = (int*)(ws + 11395072);          // 65,552
    int*   cursor = (int*)(ws + 11460624);          // 65,536
    unsigned* ep  = (unsigned*)(ws + 11526160);     // 1,048,576 (packed col|val)
    int*   bar    = (int*)(ws + 12574736);          // 512 ints (all barrier counters)

    hipMemsetAsync(bar, 0, 2048, stream);

    // One fused prep kernel: zero+hist+scan+{scatter||filt||xproj}.
    k_prep<<<512, 256, 0, stream>>>(inv1_idx, phi1_idx, inv2_idx, phi2_idx,
                                    inv1_val, phi1_val, inv2_val, phi2_val,
                                    d1, d2, fea, W1, W2, item_emb, joblst,
                                    W_ih, b_ih, b_hh,
                                    counts, rowptr, cursor, ep,
                                    filt1, filt2, xp, bar);

    // RNN (blocks 0..255) runs concurrently with gather workers (256..767);
    // workers also produce g1 = gelu(res.dW+db) directly.
    k_mega<<<768, 256, 0, stream>>>(W_hh, xp, hq, hfin, bar,
                                    rowptr, ep, filt1, filt2, y1, y2,
                                    dense_W, dense_b, g1);

    k_out<<<640, 256, 0, stream>>>(g1, hfin, (float*)d_out);
}

// Round 8
// 525.365 us; speedup vs baseline: 1.1738x; 1.1198x over previous
//
#include <hip/hip_runtime.h>
#include <cstdint>
#include <cstddef>

#define NN   4096
#define LLC  50

__device__ __forceinline__ float bf2f(unsigned short u) {
    return __uint_as_float(((unsigned)u) << 16);
}
__device__ __forceinline__ unsigned short f2bf(float x) {
    unsigned b = __float_as_uint(x);
    return (unsigned short)((b + 0x7fffu + ((b >> 16) & 1u)) >> 16);
}

#if __has_builtin(__builtin_amdgcn_sdot4)
#define SDOT4(a, b, c) __builtin_amdgcn_sdot4((int)(a), (int)(b), (c), false)
#else
__device__ __forceinline__ int sdot4_sw(unsigned a, unsigned b, int c) {
    c += (int)(signed char)(a) * (int)(signed char)(b);
    c += (int)(signed char)(a >> 8) * (int)(signed char)(b >> 8);
    c += (int)(signed char)(a >> 16) * (int)(signed char)(b >> 16);
    c += (int)(signed char)(a >> 24) * (int)(signed char)(b >> 24);
    return c;
}
#define SDOT4(a, b, c) sdot4_sw((a), (b), (c))
#endif

// sum across 64 lanes via DPP (VALU pipe); total lands in lane 63
#define DPPADD(v, ctrl, rmask) \
    ((v) + __builtin_amdgcn_update_dpp(0, (v), (ctrl), (rmask), 0xf, true))
__device__ __forceinline__ int wred64(int v) {
    v = DPPADD(v, 0x111, 0xf);   // row_shr:1
    v = DPPADD(v, 0x112, 0xf);   // row_shr:2
    v = DPPADD(v, 0x114, 0xf);   // row_shr:4
    v = DPPADD(v, 0x118, 0xf);   // row_shr:8
    v = DPPADD(v, 0x142, 0xa);   // row_bcast15
    v = DPPADD(v, 0x143, 0xc);   // row_bcast31 -> lane63=total
    return v;
}

// ---- CSR build: LDS-privatized histogram -> scan -> packed scatter ----------
// (Round-5-exact serial kernels: the atomic-heavy work stays OUT of the RNN
// window — round-6 lesson. Round-7 lesson: PBAR-phased in-kernel fusion of
// these is ~67us SLOWER than separate kernels; keep them separate.)
__global__ __launch_bounds__(256) void k_hist(const int* __restrict__ i0, const int* __restrict__ i1,
                                              const int* __restrict__ i2, const int* __restrict__ i3,
                                              int* __restrict__ counts) {
    __shared__ int lc[4096];
    int t = threadIdx.x;
#pragma unroll
    for (int i = 0; i < 16; ++i) lc[t + i * 256] = 0;
    __syncthreads();
    unsigned blk = blockIdx.x;              // 256: s = blk>>4, chunk = blk&15
    unsigned s = blk >> 4, ch = blk & 15;
    unsigned m = s >> 2, b = s & 3;
    const int* ip = (m == 0) ? i0 : (m == 1) ? i1 : (m == 2) ? i2 : i3;
    unsigned base = b * 131072u + ch * 4096u;
#pragma unroll
    for (int i = 0; i < 16; ++i) {
        int r = ip[base + t + i * 256];
        atomicAdd(&lc[r], 1);
    }
    __syncthreads();
    int* cs = counts + s * 4096;
#pragma unroll
    for (int i = 0; i < 16; ++i) {
        int v = lc[t + i * 256];
        if (v) atomicAdd(cs + t + i * 256, v);
    }
}

__global__ __launch_bounds__(256) void k_scan(const int* __restrict__ counts,
                                              int* __restrict__ rowptr,
                                              int* __restrict__ cursor) {
    int s = blockIdx.x, t = threadIdx.x;
    int loc[16];
    int base = t * 16;
    const int* cs = counts + s * 4096;
    int run = 0;
#pragma unroll
    for (int i = 0; i < 16; ++i) { loc[i] = run; run += cs[base + i]; }
    int total = run;
    int lane = t & 63, wv = t >> 6;
    int v = total;
#pragma unroll
    for (int d = 1; d < 64; d <<= 1) { int u = __shfl_up(v, d, 64); if (lane >= d) v += u; }
    __shared__ int wt[4];
    if (lane == 63) wt[wv] = v;
    __syncthreads();
    int pre = v - total;
    for (int i = 0; i < wv; ++i) pre += wt[i];
    int* rp = rowptr + s * 4097;
    int* cu = cursor + s * 4096;
#pragma unroll
    for (int i = 0; i < 16; ++i) { rp[base + i] = pre + loc[i]; cu[base + i] = pre + loc[i]; }
    if (t == 255) rp[4096] = pre + total;
}

__global__ __launch_bounds__(256) void k_scatter(const int* __restrict__ i0, const int* __restrict__ i1,
                                                 const int* __restrict__ i2, const int* __restrict__ i3,
                                                 const float* __restrict__ v0, const float* __restrict__ v1,
                                                 const float* __restrict__ v2, const float* __restrict__ v3,
                                                 const float* __restrict__ d1, const float* __restrict__ d2,
                                                 int* __restrict__ cursor,
                                                 unsigned* __restrict__ ep) {
    unsigned gid = blockIdx.x * 256 + threadIdx.x;
    unsigned s = gid >> 16, e = gid & 65535;
    unsigned m = s >> 2, b = s & 3;
    const int* ip = (m == 0) ? i0 : (m == 1) ? i1 : (m == 2) ? i2 : i3;
    const float* vp = (m == 0) ? v0 : (m == 1) ? v1 : (m == 2) ? v2 : v3;
    int r = ip[(size_t)b * 131072 + e];
    int c = ip[(size_t)b * 131072 + 65536 + e];
    float v = vp[(size_t)b * 65536 + e];
    if (m == 1) v *= d1[c];
    if (m == 3) v *= d2[c];
    int pos = atomicAdd(cursor + s * 4096 + r, 1);
    ep[(size_t)s * 65536 + pos] = ((unsigned)c << 16) | (unsigned)f2bf(v);   // col|bf16(val)
}

// ---- xproj[p=l*4+b][n] — serial pre-kernel (RNN step 0 reads xp at once) ----
__global__ __launch_bounds__(256) void k_xproj(const float* __restrict__ item_emb,
                                               const int* __restrict__ joblst,
                                               const float* __restrict__ W_ih,
                                               const float* __restrict__ b_ih,
                                               const float* __restrict__ b_hh,
                                               float* __restrict__ xp) {
    __shared__ float sx[8][128];
    int t = threadIdx.x;
    int n = blockIdx.x * 256 + t;
    int p0 = blockIdx.y * 8;
#pragma unroll
    for (int i = 0; i < 4; ++i) {
        int e2 = t + i * 256;
        int rr = e2 >> 7, c = e2 & 127;
        int p = p0 + rr;
        int b = p & 3, l = p >> 2;
        int j = joblst[b * LLC + l];
        sx[rr][c] = item_emb[(size_t)j * 128 + c];
    }
    __syncthreads();
    float acc[8];
#pragma unroll
    for (int r = 0; r < 8; ++r) acc[r] = 0.f;
    const float* wn = W_ih + (size_t)n * 128;
    for (int c = 0; c < 128; c += 4) {
        float4 w = *(const float4*)(wn + c);
#pragma unroll
        for (int r = 0; r < 8; ++r) {
            float4 xr = *(const float4*)&sx[r][c];
            acc[r] += xr.x * w.x + xr.y * w.y + xr.z * w.z + xr.w * w.w;
        }
    }
    float bias = b_ih[n] + b_hh[n];
#pragma unroll
    for (int r = 0; r < 8; ++r) xp[(size_t)(p0 + r) * NN + n] = acc[r] + bias;
}

// ---- gather edge accumulation: 2 features/lane, 8-deep pipelined, plain
// (L1/L2-cached) loads. FP accumulation order is strictly edge-sequential.
__device__ __forceinline__ void row_acc(const unsigned* __restrict__ eps, int e0, int e1,
                                        const unsigned* __restrict__ Xd, unsigned bbase,
                                        unsigned lane, float& a0, float& a1) {
    int e = e0;
    for (; e + 8 <= e1; e += 8) {
        unsigned p[8], x[8];
#pragma unroll
        for (int i = 0; i < 8; ++i) p[i] = eps[e + i];
#pragma unroll
        for (int i = 0; i < 8; ++i)
            x[i] = Xd[((size_t)(bbase + (p[i] >> 16)) << 6) + lane];
#pragma unroll
        for (int i = 0; i < 8; ++i) {
            float v = bf2f((unsigned short)p[i]);
            a0 += v * bf2f((unsigned short)x[i]);
            a1 += v * bf2f((unsigned short)(x[i] >> 16));
        }
    }
    for (; e < e1; ++e) {
        unsigned pp = eps[e];
        unsigned xw = Xd[((size_t)(bbase + (pp >> 16)) << 6) + lane];
        float v = bf2f((unsigned short)pp);
        a0 += v * bf2f((unsigned short)xw);
        a1 += v * bf2f((unsigned short)(xw >> 16));
    }
}

// Worker fence barrier: vmcnt-drain -> release(wbl2) -> arrive -> spin ->
// acquire(inv). Proven mid-RNN at bar[320] (rounds 2-5, absmax 0).
#define WFENCE_BAR(IDX)                                                        \
    __syncthreads();                                                           \
    if (t == 0) {                                                              \
        __builtin_amdgcn_fence(__ATOMIC_RELEASE, "agent");                     \
        __hip_atomic_fetch_add(&bar[IDX], 1, __ATOMIC_RELAXED,                 \
                               __HIP_MEMORY_SCOPE_AGENT);                      \
        while (__hip_atomic_load(&bar[IDX], __ATOMIC_RELAXED,                  \
                                 __HIP_MEMORY_SCOPE_AGENT) < 512)              \
            __builtin_amdgcn_s_sleep(4);                                       \
        __builtin_amdgcn_fence(__ATOMIC_ACQUIRE, "agent");                     \
    }                                                                          \
    __syncthreads();

// ---- MEGA: RNN (blocks 0..255) || filt+gathers (blocks 256..767) ------------
// RNN path: byte-identical to round 2 (proven 293us with workers).
// Workers (all atomic-free, plain cached loads/stores):
//   F: filt1/filt2 = fea@W1, fea@W2  (512 blk x 32 rows; round-6 bit-exact body)
//   WFENCE_BAR(312)
//   D: gather1 (y = inv@filt)
//   WFENCE_BAR(320)
//   E: gather2 + fused gelu(res.dW+db) -> g1
// Round-6 lesson honored: no device atomics in the RNN window; only one extra
// fence-barrier vs round 5. Residency: 80 VGPR -> 4 blocks/CU capacity >= 3
// needed (proven at 768 blocks in round 6); barriers deadlock-free.
__global__ __launch_bounds__(256, 2) void k_mega(
        const float* __restrict__ W_hh,
        const float* __restrict__ xp,
        unsigned* __restrict__ hq,           // [2][4096]
        float* __restrict__ hfin,
        int* __restrict__ bar,               // [512] ints (zeroed)
        const int* __restrict__ rowptr,
        const unsigned* __restrict__ ep,
        unsigned short* __restrict__ filt1,
        unsigned short* __restrict__ filt2,
        unsigned short* __restrict__ y1,
        unsigned short* __restrict__ y2,
        const float* __restrict__ dW,
        const float* __restrict__ db,
        float* __restrict__ g1,
        const float* __restrict__ fea,
        const float* __restrict__ W1,
        const float* __restrict__ W2) {
    __shared__ unsigned hs[4352];              // RNN h / filt stage / g1 row-stage
    __shared__ int red[4][16];
    __shared__ unsigned char hpk[4][4][4];     // [wv][b][rr]
    int t = threadIdx.x;
    int lane = t & 63, wv = t >> 6;
    int blk = blockIdx.x;

    if (blk >= 256) {
        // ================== WORKER PATH ======================================
        int w = blk - 256;                     // 0..511; blk%8 == w%8 (XCD heuristic)
        int c7 = w & 7;
        // ---- phase F: filt (rows w*32..w*32+31; bit-exact round-6 body) ----
        {
            int rb = w * 32;
            float* sfea = (float*)hs;          // [32][128] = 16KB
#pragma unroll
            for (int i = 0; i < 16; ++i) {
                int idx = t + i * 256;
                sfea[idx] = fea[(size_t)rb * 128 + idx];
            }
            __syncthreads();
            int half = t >> 7, tc = t & 127;
            const float* sf = sfea + half * 2048;   // 16 rows x 128
            float a1[16], a2[16];
#pragma unroll
            for (int r = 0; r < 16; ++r) { a1[r] = 0.f; a2[r] = 0.f; }
            for (int c = 0; c < 128; c += 4) {
                float w10 = W1[(c + 0) * 128 + tc], w11 = W1[(c + 1) * 128 + tc];
                float w12 = W1[(c + 2) * 128 + tc], w13 = W1[(c + 3) * 128 + tc];
                float w20 = W2[(c + 0) * 128 + tc], w21 = W2[(c + 1) * 128 + tc];
                float w22 = W2[(c + 2) * 128 + tc], w23 = W2[(c + 3) * 128 + tc];
#pragma unroll
                for (int r = 0; r < 16; ++r) {
                    float4 f = *(const float4*)&sf[r * 128 + c];
                    a1[r] += f.x * w10 + f.y * w11 + f.z * w12 + f.w * w13;
                    a2[r] += f.x * w20 + f.y * w21 + f.z * w22 + f.w * w23;
                }
            }
#pragma unroll
            for (int r = 0; r < 16; ++r) {
                size_t o = (size_t)(rb + half * 16 + r) * 128 + tc;
                filt1[o] = f2bf(a1[r]);
                filt2[o] = f2bf(a2[r]);
            }
        }
        WFENCE_BAR(312)
        // ---- phase D: gather1 (y = inv@filt) -------------------------------
        {
            unsigned mm = c7 & 1, b = (unsigned)c7 >> 1;
            int s = (mm ? 8 : 0) + (int)b;
            const unsigned* Xd = (const unsigned*)(mm ? filt2 : filt1);
            unsigned* Yd = (unsigned*)(mm ? y2 : y1);
            const int* rp = rowptr + s * 4097;
            const unsigned* eps = ep + (size_t)s * 65536;
            unsigned bbase = b * 4096;
            int g = w >> 3;                    // 0..63
            int row0 = (g * 4 + wv) * 16;
            for (int rr = 0; rr < 16; ++rr) {
                int row = row0 + rr;
                float a0 = 0.f, a1 = 0.f;
                row_acc(eps, rp[row], rp[row + 1], Xd, bbase, lane, a0, a1);
                Yd[((size_t)(bbase + row) << 6) + lane] =
                    (unsigned)f2bf(a0) | ((unsigned)f2bf(a1) << 16);
            }
        }
        WFENCE_BAR(320)
        // ---- phase E: gather2 rows -> gelu(row.dW[k]+db[k]) -> g1 ----------
        {
            unsigned b = (unsigned)c7 >> 1;
            unsigned bbase = b * 4096;
            const int* rpA = rowptr + (4 + (int)b) * 4097;
            const int* rpB = rowptr + (12 + (int)b) * 4097;
            const unsigned* epA = ep + (size_t)(4 + b) * 65536;
            const unsigned* epB = ep + (size_t)(12 + b) * 65536;
            const unsigned* y1d = (const unsigned*)y1;
            const unsigned* y2d = (const unsigned*)y2;
            int g2 = (w >> 3) * 2 + (w & 1);   // 0..127
            int row0 = (g2 * 4 + wv) * 8;
            float* fs = (float*)hs + wv * 1056;        // 8 rows x 132 (padded)
            for (int rr = 0; rr < 8; ++rr) {
                int row = row0 + rr;
                float a0 = 0.f, a1 = 0.f;
                row_acc(epA, rpA[row], rpA[row + 1], y1d, bbase, lane, a0, a1);
                row_acc(epB, rpB[row], rpB[row + 1], y2d, bbase, lane, a0, a1);
                *(float2*)(fs + rr * 132 + 2 * lane) = make_float2(a0, a1);
            }
#pragma unroll
            for (int pass = 0; pass < 2; ++pass) {
                int task = lane + pass * 64;
                if (task < 80) {
                    int rr = task / 10, k = task - rr * 10;
                    const float* rrp = fs + rr * 132;
                    const float4* wk4 = (const float4*)(dW + (size_t)k * 128);
                    float acc = 0.f;
#pragma unroll
                    for (int c4 = 0; c4 < 32; ++c4) {
                        float4 a = *(const float4*)(rrp + c4 * 4);
                        float4 wq = wk4[c4];
                        acc += a.x * wq.x + a.y * wq.y + a.z * wq.z + a.w * wq.w;
                    }
                    float pre = acc + db[k];
                    float gg = 0.5f * pre * (1.f + erff(pre * 0.70710678118f));
                    g1[(size_t)(bbase + row0 + rr) * 10 + k] = gg;
                }
            }
        }
        return;
    }

    // ========================== RNN PATH (blocks 0..255) =====================
    // (byte-identical to round 2's RNN path)
    int row_base = ((blk & 7) * 32 + (blk >> 3)) * 16;   // XCD-sliced: 512 rows/XCD
    int wrow = row_base + wv * 4;

    uint4 W[4][4];
    {
        const float* wsrc = W_hh + (size_t)wrow * 4096;
#pragma unroll
        for (int r = 0; r < 4; ++r)
#pragma unroll
            for (int k4 = 0; k4 < 4; ++k4) {
                unsigned q[4];
#pragma unroll
                for (int i = 0; i < 4; ++i) {
                    const float* p = wsrc + (size_t)r * 4096 + (lane * 16 + k4 * 4 + i) * 4;
                    float4 w = *(const float4*)p;
                    int q0 = (int)rintf(fminf(fmaxf(w.x * 8192.f, -127.f), 127.f));
                    int q1 = (int)rintf(fminf(fmaxf(w.y * 8192.f, -127.f), 127.f));
                    int q2 = (int)rintf(fminf(fmaxf(w.z * 8192.f, -127.f), 127.f));
                    int q3 = (int)rintf(fminf(fmaxf(w.w * 8192.f, -127.f), 127.f));
                    q[i] = (q0 & 0xff) | ((q1 & 0xff) << 8) | ((q2 & 0xff) << 16) | ((q3 & 0xff) << 24);
                }
                W[r][k4] = make_uint4(q[0], q[1], q[2], q[3]);
            }
    }

    const float SC = 1.f / (8192.f * 127.f);

    for (int l = 0; l < LLC; ++l) {
        if (l > 0) {
            const unsigned* src = hq + (size_t)((l - 1) & 1) * 4096;
            unsigned sval[16];
#pragma unroll
            for (int k = 0; k < 16; ++k)
                sval[k] = __hip_atomic_load(src + t + k * 256, __ATOMIC_RELAXED,
                                            __HIP_MEMORY_SCOPE_AGENT);
#pragma unroll
            for (int k = 0; k < 16; ++k) hs[t + k * 256] = sval[k];
            __syncthreads();

            __builtin_amdgcn_s_setprio(1);
            uint4 H[4][4];
#pragma unroll
            for (int b = 0; b < 4; ++b)
#pragma unroll
                for (int k4 = 0; k4 < 4; ++k4)
                    H[b][k4] = ((const uint4*)hs)[k4 * 256 + b * 64 + lane];
            int acc[4][4];
#pragma unroll
            for (int r = 0; r < 4; ++r)
#pragma unroll
                for (int b = 0; b < 4; ++b) acc[r][b] = 0;
#pragma unroll
            for (int k4 = 0; k4 < 4; ++k4)
#pragma unroll
                for (int r = 0; r < 4; ++r)
#pragma unroll
                    for (int b = 0; b < 4; ++b) {
                        acc[r][b] = SDOT4(W[r][k4].x, H[b][k4].x, acc[r][b]);
                        acc[r][b] = SDOT4(W[r][k4].y, H[b][k4].y, acc[r][b]);
                        acc[r][b] = SDOT4(W[r][k4].z, H[b][k4].z, acc[r][b]);
                        acc[r][b] = SDOT4(W[r][k4].w, H[b][k4].w, acc[r][b]);
                    }
#pragma unroll
            for (int r = 0; r < 4; ++r)
#pragma unroll
                for (int b = 0; b < 4; ++b) acc[r][b] = wred64(acc[r][b]);
            if (lane == 63) {
#pragma unroll
                for (int b = 0; b < 4; ++b) {
                    int4 q = { acc[0][b], acc[1][b], acc[2][b], acc[3][b] };
                    *(int4*)&red[wv][b * 4] = q;
                }
            }
            __builtin_amdgcn_s_setprio(0);
        }
        if (lane < 16) {
            int b = lane >> 2, rr = lane & 3;
            int row = wrow + rr;
            float a = (l > 0) ? (float)red[wv][lane] * SC : 0.f;
            float pre = a + xp[(size_t)(l * 4 + b) * NN + row];
            float hnew = tanhf(pre);
            if (l == LLC - 1) hfin[(size_t)b * NN + row] = hnew;
            int q = (int)rintf(hnew * 127.f);
            hpk[wv][b][rr] = (unsigned char)(q & 0xff);
        }
        if (l < LLC - 1) {
            if (lane < 4) {
                int b = lane;
                unsigned d = *(const unsigned*)&hpk[wv][b][0];
                int hk = (row_base >> 2) + wv;
                int phys = ((hk >> 2) & 3) * 1024 + b * 256 + (hk >> 4) * 4 + (hk & 3);
                __hip_atomic_store(hq + (size_t)(l & 1) * 4096 + phys, d,
                                   __ATOMIC_RELAXED, __HIP_MEMORY_SCOPE_AGENT);
            }
            __syncthreads();
            if (t == 0) {
                int g = blk & 7;
                int old = __hip_atomic_fetch_add(&bar[g * 32], 1, __ATOMIC_RELAXED,
                                                 __HIP_MEMORY_SCOPE_AGENT);
                if ((old & 31) == 31)
                    __hip_atomic_fetch_add(&bar[256], 1, __ATOMIC_RELAXED,
                                           __HIP_MEMORY_SCOPE_AGENT);
                int target = 8 * (l + 1);
                while (__hip_atomic_load(&bar[256], __ATOMIC_RELAXED,
                                         __HIP_MEMORY_SCOPE_AGENT) < target)
                    __builtin_amdgcn_s_sleep(2);
            }
            __syncthreads();
        }
    }
}

// ---- out = sigmoid( g1 * gelu(hfin) ), elementwise -------------------------
__global__ __launch_bounds__(256) void k_out(const float* __restrict__ g1,
                                             const float* __restrict__ hfin,
                                             float* __restrict__ out) {
    int i = blockIdx.x * 256 + threadIdx.x;        // [0, 163840)
    int grow = i / 10;
    float e = hfin[grow];
    float ge = 0.5f * e * (1.f + erff(e * 0.70710678118f));
    out[i] = 1.f / (1.f + __expf(-g1[i] * ge));
}

extern "C" void kernel_launch(void* const* d_in, const int* in_sizes, int n_in,
                              void* d_out, int out_size, void* d_ws, size_t ws_size,
                              hipStream_t stream) {
    const int*   phi1_idx = (const int*)d_in[0];
    const float* phi1_val = (const float*)d_in[1];
    const int*   inv1_idx = (const int*)d_in[2];
    const float* inv1_val = (const float*)d_in[3];
    const int*   phi2_idx = (const int*)d_in[4];
    const float* phi2_val = (const float*)d_in[5];
    const int*   inv2_idx = (const int*)d_in[6];
    const float* inv2_val = (const float*)d_in[7];
    const float* fea      = (const float*)d_in[8];
    const int*   joblst   = (const int*)d_in[9];
    const float* W1       = (const float*)d_in[10];
    const float* d1       = (const float*)d_in[11];
    const float* W2       = (const float*)d_in[12];
    const float* d2       = (const float*)d_in[13];
    const float* W_ih     = (const float*)d_in[14];
    const float* W_hh     = (const float*)d_in[15];
    const float* b_ih     = (const float*)d_in[16];
    const float* b_hh     = (const float*)d_in[17];
    const float* dense_W  = (const float*)d_in[18];
    const float* dense_b  = (const float*)d_in[19];
    const float* item_emb = (const float*)d_in[20];

    float* ws = (float*)d_ws;                       // slot = 4B
    unsigned short* filt1 = (unsigned short*)ws;            // 1,048,576 slots
    unsigned short* filt2 = (unsigned short*)(ws + 1048576);
    unsigned short* y1    = (unsigned short*)(ws + 2097152);
    unsigned short* y2    = (unsigned short*)(ws + 3145728);
    float* g1   = ws + 4194304;                     // 163,840 slots
    float* xp   = ws + 6291456;                     // 819,200
    float* hfin = ws + 7110656;                     // 16,384
    unsigned* hq  = (unsigned*)(ws + 7127040);      // 8,192 (2 x 4096 dwords)
    int*   counts = (int*)(ws + 11329536);          // 65,536
    int*   rowptr = (int*)(ws + 11395072);          // 65,552
    int*   cursor = (int*)(ws + 11460624);          // 65,536
    unsigned* ep  = (unsigned*)(ws + 11526160);     // 1,048,576 (packed col|val)
    int*   bar    = (int*)(ws + 12574736);          // 512 ints (all barrier counters)

    hipMemsetAsync(counts, 0, 16 * 4096 * sizeof(int), stream);
    hipMemsetAsync(bar, 0, 2048, stream);

    k_xproj<<<dim3(16, 25), 256, 0, stream>>>(item_emb, joblst, W_ih, b_ih, b_hh, xp);

    k_hist<<<256, 256, 0, stream>>>(inv1_idx, phi1_idx, inv2_idx, phi2_idx, counts);
    k_scan<<<16, 256, 0, stream>>>(counts, rowptr, cursor);
    k_scatter<<<4096, 256, 0, stream>>>(inv1_idx, phi1_idx, inv2_idx, phi2_idx,
                                        inv1_val, phi1_val, inv2_val, phi2_val,
                                        d1, d2, cursor, ep);

    // RNN (blocks 0..255) || workers (256..767: filt -> gather1 -> gather2+g1).
    k_mega<<<768, 256, 0, stream>>>(W_hh, xp, hq, hfin, bar,
                                    rowptr, ep, filt1, filt2, y1, y2,
                                    dense_W, dense_b, g1, fea, W1, W2);

    k_out<<<640, 256, 0, stream>>>(g1, hfin, (float*)d_out);
}

// Round 9
// 502.359 us; speedup vs baseline: 1.2275x; 1.0458x over previous
//
#include <hip/hip_runtime.h>
#include <cstdint>
#include <cstddef>

#define NN   4096
#define LLC  50

__device__ __forceinline__ float bf2f(unsigned short u) {
    return __uint_as_float(((unsigned)u) << 16);
}
__device__ __forceinline__ unsigned short f2bf(float x) {
    unsigned b = __float_as_uint(x);
    return (unsigned short)((b + 0x7fffu + ((b >> 16) & 1u)) >> 16);
}

#if __has_builtin(__builtin_amdgcn_sdot4)
#define SDOT4(a, b, c) __builtin_amdgcn_sdot4((int)(a), (int)(b), (c), false)
#else
__device__ __forceinline__ int sdot4_sw(unsigned a, unsigned b, int c) {
    c += (int)(signed char)(a) * (int)(signed char)(b);
    c += (int)(signed char)(a >> 8) * (int)(signed char)(b >> 8);
    c += (int)(signed char)(a >> 16) * (int)(signed char)(b >> 16);
    c += (int)(signed char)(a >> 24) * (int)(signed char)(b >> 24);
    return c;
}
#define SDOT4(a, b, c) sdot4_sw((a), (b), (c))
#endif

// sum across 64 lanes via DPP (VALU pipe); total lands in lane 63
#define DPPADD(v, ctrl, rmask) \
    ((v) + __builtin_amdgcn_update_dpp(0, (v), (ctrl), (rmask), 0xf, true))
__device__ __forceinline__ int wred64(int v) {
    v = DPPADD(v, 0x111, 0xf);   // row_shr:1
    v = DPPADD(v, 0x112, 0xf);   // row_shr:2
    v = DPPADD(v, 0x114, 0xf);   // row_shr:4
    v = DPPADD(v, 0x118, 0xf);   // row_shr:8
    v = DPPADD(v, 0x142, 0xa);   // row_bcast15
    v = DPPADD(v, 0x143, 0xc);   // row_bcast31 -> lane63=total
    return v;
}

// ---- PREP: barrier-free block-range fusion of independent work --------------
//   blk   0..15 : hist+scan per s (LDS histogram of all 65536 edges -> prefix
//                 scan in the SAME LDS -> rowptr/cursor; counts buffer gone)
//   blk  16..143: xproj (round-7-verified 25-row body)
//   blk 144..655: filt  (round-8-verified 32-row body)
// NO internal barriers (round-7 lesson: PBAR fusion loses; this is pure
// concatenation = separate kernels minus launch gaps). All bodies bit-exact
// vs their standalone ancestors.
__global__ __launch_bounds__(256) void k_prep(
        const int* __restrict__ i0, const int* __restrict__ i1,
        const int* __restrict__ i2, const int* __restrict__ i3,
        const float* __restrict__ fea,
        const float* __restrict__ W1, const float* __restrict__ W2,
        const float* __restrict__ item_emb, const int* __restrict__ joblst,
        const float* __restrict__ W_ih,
        const float* __restrict__ b_ih, const float* __restrict__ b_hh,
        int* __restrict__ rowptr, int* __restrict__ cursor,
        unsigned short* __restrict__ filt1, unsigned short* __restrict__ filt2,
        float* __restrict__ xp) {
    __shared__ float smem[4096];               // 16KB: hist lc / xproj sx / filt stage
    __shared__ int wt4[4];
    int t = threadIdx.x;
    int lane = t & 63, wv = t >> 6;
    int blk = blockIdx.x;

    if (blk < 16) {
        // ---------------- hist + scan, one block per s ----------------------
        int s = blk;
        int* lc = (int*)smem;
#pragma unroll
        for (int i = 0; i < 16; ++i) lc[t + i * 256] = 0;
        __syncthreads();
        unsigned m = (unsigned)s >> 2, b = (unsigned)s & 3;
        const int* ip = (m == 0) ? i0 : (m == 1) ? i1 : (m == 2) ? i2 : i3;
        const int4* ip4 = (const int4*)(ip + (size_t)b * 131072);
#pragma unroll 4
        for (int i = 0; i < 64; ++i) {
            int4 r4 = ip4[i * 256 + t];
            atomicAdd(&lc[r4.x], 1);
            atomicAdd(&lc[r4.y], 1);
            atomicAdd(&lc[r4.z], 1);
            atomicAdd(&lc[r4.w], 1);
        }
        __syncthreads();
        // prefix scan (k_scan body, counts -> lc)
        int loc[16];
        int base = t * 16;
        int run = 0;
#pragma unroll
        for (int i = 0; i < 16; ++i) { loc[i] = run; run += lc[base + i]; }
        int total = run;
        int v = total;
#pragma unroll
        for (int d = 1; d < 64; d <<= 1) { int u = __shfl_up(v, d, 64); if (lane >= d) v += u; }
        if (lane == 63) wt4[wv] = v;
        __syncthreads();
        int pre = v - total;
        for (int i = 0; i < wv; ++i) pre += wt4[i];
        int* rp = rowptr + s * 4097;
        int* cu = cursor + s * 4096;
#pragma unroll
        for (int i = 0; i < 16; ++i) { rp[base + i] = pre + loc[i]; cu[base + i] = pre + loc[i]; }
        if (t == 255) rp[4096] = pre + total;
    } else if (blk < 144) {
        // ---------------- xproj (round-7-verified body) ---------------------
        int wx = blk - 16;
        int nb = wx & 15, pb = wx >> 4;        // pb 0..7
        int p0 = pb * 25;
        for (int idx = t; idx < 25 * 128; idx += 256) {
            int rr = idx >> 7, c = idx & 127;
            int p = p0 + rr;
            int b = p & 3, l = p >> 2;
            int j = joblst[b * LLC + l];
            smem[idx] = item_emb[(size_t)j * 128 + c];
        }
        __syncthreads();
        int n = nb * 256 + t;
        float acc[25];
#pragma unroll
        for (int r = 0; r < 25; ++r) acc[r] = 0.f;
        const float* wn = W_ih + (size_t)n * 128;
        for (int c = 0; c < 128; c += 4) {
            float4 wq = *(const float4*)(wn + c);
#pragma unroll
            for (int r = 0; r < 25; ++r) {
                float4 xr = *(const float4*)&smem[r * 128 + c];
                acc[r] += xr.x * wq.x + xr.y * wq.y + xr.z * wq.z + xr.w * wq.w;
            }
        }
        float bias = b_ih[n] + b_hh[n];
#pragma unroll
        for (int r = 0; r < 25; ++r) xp[(size_t)(p0 + r) * NN + n] = acc[r] + bias;
    } else {
        // ---------------- filt (round-8-verified 32-row body) ---------------
        int rb = (blk - 144) * 32;
#pragma unroll
        for (int i = 0; i < 16; ++i) {
            int idx = t + i * 256;
            smem[idx] = fea[(size_t)rb * 128 + idx];
        }
        __syncthreads();
        int half = t >> 7, tc = t & 127;
        const float* sf = smem + half * 2048;  // 16 rows x 128
        float a1[16], a2[16];
#pragma unroll
        for (int r = 0; r < 16; ++r) { a1[r] = 0.f; a2[r] = 0.f; }
        for (int c = 0; c < 128; c += 4) {
            float w10 = W1[(c + 0) * 128 + tc], w11 = W1[(c + 1) * 128 + tc];
            float w12 = W1[(c + 2) * 128 + tc], w13 = W1[(c + 3) * 128 + tc];
            float w20 = W2[(c + 0) * 128 + tc], w21 = W2[(c + 1) * 128 + tc];
            float w22 = W2[(c + 2) * 128 + tc], w23 = W2[(c + 3) * 128 + tc];
#pragma unroll
            for (int r = 0; r < 16; ++r) {
                float4 f = *(const float4*)&sf[r * 128 + c];
                a1[r] += f.x * w10 + f.y * w11 + f.z * w12 + f.w * w13;
                a2[r] += f.x * w20 + f.y * w21 + f.z * w22 + f.w * w23;
            }
        }
#pragma unroll
        for (int r = 0; r < 16; ++r) {
            size_t o = (size_t)(rb + half * 16 + r) * 128 + tc;
            filt1[o] = f2bf(a1[r]);
            filt2[o] = f2bf(a2[r]);
        }
    }
}

__global__ __launch_bounds__(256) void k_scatter(const int* __restrict__ i0, const int* __restrict__ i1,
                                                 const int* __restrict__ i2, const int* __restrict__ i3,
                                                 const float* __restrict__ v0, const float* __restrict__ v1,
                                                 const float* __restrict__ v2, const float* __restrict__ v3,
                                                 const float* __restrict__ d1, const float* __restrict__ d2,
                                                 int* __restrict__ cursor,
                                                 unsigned* __restrict__ ep) {
    unsigned gid = blockIdx.x * 256 + threadIdx.x;
    unsigned s = gid >> 16, e = gid & 65535;
    unsigned m = s >> 2, b = s & 3;
    const int* ip = (m == 0) ? i0 : (m == 1) ? i1 : (m == 2) ? i2 : i3;
    const float* vp = (m == 0) ? v0 : (m == 1) ? v1 : (m == 2) ? v2 : v3;
    int r = ip[(size_t)b * 131072 + e];
    int c = ip[(size_t)b * 131072 + 65536 + e];
    float v = vp[(size_t)b * 65536 + e];
    if (m == 1) v *= d1[c];
    if (m == 3) v *= d2[c];
    int pos = atomicAdd(cursor + s * 4096 + r, 1);
    ep[(size_t)s * 65536 + pos] = ((unsigned)c << 16) | (unsigned)f2bf(v);   // col|bf16(val)
}

// ---- gather edge accumulation: 2 features/lane, 8-deep pipelined, plain
// (L1/L2-cached) loads. FP accumulation order is strictly edge-sequential.
__device__ __forceinline__ void row_acc(const unsigned* __restrict__ eps, int e0, int e1,
                                        const unsigned* __restrict__ Xd, unsigned bbase,
                                        unsigned lane, float& a0, float& a1) {
    int e = e0;
    for (; e + 8 <= e1; e += 8) {
        unsigned p[8], x[8];
#pragma unroll
        for (int i = 0; i < 8; ++i) p[i] = eps[e + i];
#pragma unroll
        for (int i = 0; i < 8; ++i)
            x[i] = Xd[((size_t)(bbase + (p[i] >> 16)) << 6) + lane];
#pragma unroll
        for (int i = 0; i < 8; ++i) {
            float v = bf2f((unsigned short)p[i]);
            a0 += v * bf2f((unsigned short)x[i]);
            a1 += v * bf2f((unsigned short)(x[i] >> 16));
        }
    }
    for (; e < e1; ++e) {
        unsigned pp = eps[e];
        unsigned xw = Xd[((size_t)(bbase + (pp >> 16)) << 6) + lane];
        float v = bf2f((unsigned short)pp);
        a0 += v * bf2f((unsigned short)xw);
        a1 += v * bf2f((unsigned short)(xw >> 16));
    }
}

// ---- MEGA: RNN (blocks 0..255) || sparse gathers (blocks 256..767) ----------
// Workers: ROUND-5 EXACT (gather1 / fence-barrier / gather2+g1) plus a final
// release+arrive at bar[352]. RNN path: round-2-exact steps 0..48; at l=49 the
// block waits for bar[352] (workers finished ~100us earlier -> instant), then
// computes out = sigmoid(g1 * gelu(h_final)) directly (k_out's exact math),
// reading g1 via agent-scope loads (post-release -> coherence-point visible).
__global__ __launch_bounds__(256, 2) void k_mega(
        const float* __restrict__ W_hh,
        const float* __restrict__ xp,
        unsigned* __restrict__ hq,           // [2][4096]
        int* __restrict__ bar,               // [512] ints (zeroed)
        const int* __restrict__ rowptr,
        const unsigned* __restrict__ ep,
        const unsigned short* __restrict__ filt1,
        const unsigned short* __restrict__ filt2,
        unsigned short* __restrict__ y1,
        unsigned short* __restrict__ y2,
        const float* __restrict__ dW,
        const float* __restrict__ db,
        float* __restrict__ g1,
        float* __restrict__ out) {
    __shared__ unsigned hs[4352];              // RNN h / worker row-stage
    __shared__ int red[4][16];
    __shared__ unsigned char hpk[4][4][4];     // [wv][b][rr]
    int t = threadIdx.x;
    int lane = t & 63, wv = t >> 6;
    int blk = blockIdx.x;

    if (blk >= 256) {
        // ================== WORKER PATH: gather1 then gather2+dot ============
        int w = blk - 256;                     // 0..511; blk%8 == w%8 (XCD heuristic)
        int c7 = w & 7;
        // ---- phase 1: y = inv@filt; combo (mm,b) pinned per XCD residue ----
        {
            unsigned mm = c7 & 1, b = (unsigned)c7 >> 1;
            int s = (mm ? 8 : 0) + (int)b;
            const unsigned* Xd = (const unsigned*)(mm ? filt2 : filt1);
            unsigned* Yd = (unsigned*)(mm ? y2 : y1);
            const int* rp = rowptr + s * 4097;
            const unsigned* eps = ep + (size_t)s * 65536;
            unsigned bbase = b * 4096;
            int g = w >> 3;                    // 0..63
            int row0 = (g * 4 + wv) * 16;
            for (int rr = 0; rr < 16; ++rr) {
                int row = row0 + rr;
                float a0 = 0.f, a1 = 0.f;
                row_acc(eps, rp[row], rp[row + 1], Xd, bbase, lane, a0, a1);
                Yd[((size_t)(bbase + row) << 6) + lane] =
                    (unsigned)f2bf(a0) | ((unsigned)f2bf(a1) << 16);
            }
        }
        // ---- worker phase barrier with cross-XCD fences (per-block) ----
        __syncthreads();                       // vmcnt(0): y stores are in L2
        if (t == 0) {
            __builtin_amdgcn_fence(__ATOMIC_RELEASE, "agent");   // wbl2 -> L3
            __hip_atomic_fetch_add(&bar[320], 1, __ATOMIC_RELAXED,
                                   __HIP_MEMORY_SCOPE_AGENT);
            while (__hip_atomic_load(&bar[320], __ATOMIC_RELAXED,
                                     __HIP_MEMORY_SCOPE_AGENT) < 512)
                __builtin_amdgcn_s_sleep(4);
            __builtin_amdgcn_fence(__ATOMIC_ACQUIRE, "agent");   // inv stale L1/L2
        }
        __syncthreads();
        // ---- phase 2: rows of phi1@y1 + phi2@y2 -> gelu(row.dW[k]+db[k]) ----
        {
            unsigned b = (unsigned)c7 >> 1;
            unsigned bbase = b * 4096;
            const int* rpA = rowptr + (4 + (int)b) * 4097;
            const int* rpB = rowptr + (12 + (int)b) * 4097;
            const unsigned* epA = ep + (size_t)(4 + b) * 65536;
            const unsigned* epB = ep + (size_t)(12 + b) * 65536;
            const unsigned* y1d = (const unsigned*)y1;
            const unsigned* y2d = (const unsigned*)y2;
            int g2 = (w >> 3) * 2 + (w & 1);   // 0..127
            int row0 = (g2 * 4 + wv) * 8;
            float* fs = (float*)hs + wv * 1056;        // 8 rows x 132 (padded)
            for (int rr = 0; rr < 8; ++rr) {
                int row = row0 + rr;
                float a0 = 0.f, a1 = 0.f;
                row_acc(epA, rpA[row], rpA[row + 1], y1d, bbase, lane, a0, a1);
                row_acc(epB, rpB[row], rpB[row + 1], y2d, bbase, lane, a0, a1);
                *(float2*)(fs + rr * 132 + 2 * lane) = make_float2(a0, a1);
            }
#pragma unroll
            for (int pass = 0; pass < 2; ++pass) {
                int task = lane + pass * 64;
                if (task < 80) {
                    int rr = task / 10, k = task - rr * 10;
                    const float* rrp = fs + rr * 132;
                    const float4* wk4 = (const float4*)(dW + (size_t)k * 128);
                    float acc = 0.f;
#pragma unroll
                    for (int c4 = 0; c4 < 32; ++c4) {
                        float4 a = *(const float4*)(rrp + c4 * 4);
                        float4 wq = wk4[c4];
                        acc += a.x * wq.x + a.y * wq.y + a.z * wq.z + a.w * wq.w;
                    }
                    float pre = acc + db[k];
                    float gg = 0.5f * pre * (1.f + erff(pre * 0.70710678118f));
                    g1[(size_t)(bbase + row0 + rr) * 10 + k] = gg;
                }
            }
        }
        // ---- signal g1 complete (release -> arrive; no spin) ----
        __syncthreads();                       // drain g1 stores to L2
        if (t == 0) {
            __builtin_amdgcn_fence(__ATOMIC_RELEASE, "agent");   // wbl2: g1 -> L3
            __hip_atomic_fetch_add(&bar[352], 1, __ATOMIC_RELAXED,
                                   __HIP_MEMORY_SCOPE_AGENT);
        }
        return;
    }

    // ========================== RNN PATH (blocks 0..255) =====================
    // (byte-identical to round 2's RNN path for steps 0..48)
    int row_base = ((blk & 7) * 32 + (blk >> 3)) * 16;   // XCD-sliced: 512 rows/XCD
    int wrow = row_base + wv * 4;

    uint4 W[4][4];
    {
        const float* wsrc = W_hh + (size_t)wrow * 4096;
#pragma unroll
        for (int r = 0; r < 4; ++r)
#pragma unroll
            for (int k4 = 0; k4 < 4; ++k4) {
                unsigned q[4];
#pragma unroll
                for (int i = 0; i < 4; ++i) {
                    const float* p = wsrc + (size_t)r * 4096 + (lane * 16 + k4 * 4 + i) * 4;
                    float4 w = *(const float4*)p;
                    int q0 = (int)rintf(fminf(fmaxf(w.x * 8192.f, -127.f), 127.f));
                    int q1 = (int)rintf(fminf(fmaxf(w.y * 8192.f, -127.f), 127.f));
                    int q2 = (int)rintf(fminf(fmaxf(w.z * 8192.f, -127.f), 127.f));
                    int q3 = (int)rintf(fminf(fmaxf(w.w * 8192.f, -127.f), 127.f));
                    q[i] = (q0 & 0xff) | ((q1 & 0xff) << 8) | ((q2 & 0xff) << 16) | ((q3 & 0xff) << 24);
                }
                W[r][k4] = make_uint4(q[0], q[1], q[2], q[3]);
            }
    }

    const float SC = 1.f / (8192.f * 127.f);

    for (int l = 0; l < LLC; ++l) {
        if (l > 0) {
            const unsigned* src = hq + (size_t)((l - 1) & 1) * 4096;
            unsigned sval[16];
#pragma unroll
            for (int k = 0; k < 16; ++k)
                sval[k] = __hip_atomic_load(src + t + k * 256, __ATOMIC_RELAXED,
                                            __HIP_MEMORY_SCOPE_AGENT);
#pragma unroll
            for (int k = 0; k < 16; ++k) hs[t + k * 256] = sval[k];
            __syncthreads();

            __builtin_amdgcn_s_setprio(1);
            uint4 H[4][4];
#pragma unroll
            for (int b = 0; b < 4; ++b)
#pragma unroll
                for (int k4 = 0; k4 < 4; ++k4)
                    H[b][k4] = ((const uint4*)hs)[k4 * 256 + b * 64 + lane];
            int acc[4][4];
#pragma unroll
            for (int r = 0; r < 4; ++r)
#pragma unroll
                for (int b = 0; b < 4; ++b) acc[r][b] = 0;
#pragma unroll
            for (int k4 = 0; k4 < 4; ++k4)
#pragma unroll
                for (int r = 0; r < 4; ++r)
#pragma unroll
                    for (int b = 0; b < 4; ++b) {
                        acc[r][b] = SDOT4(W[r][k4].x, H[b][k4].x, acc[r][b]);
                        acc[r][b] = SDOT4(W[r][k4].y, H[b][k4].y, acc[r][b]);
                        acc[r][b] = SDOT4(W[r][k4].z, H[b][k4].z, acc[r][b]);
                        acc[r][b] = SDOT4(W[r][k4].w, H[b][k4].w, acc[r][b]);
                    }
#pragma unroll
            for (int r = 0; r < 4; ++r)
#pragma unroll
                for (int b = 0; b < 4; ++b) acc[r][b] = wred64(acc[r][b]);
            if (lane == 63) {
#pragma unroll
                for (int b = 0; b < 4; ++b) {
                    int4 q = { acc[0][b], acc[1][b], acc[2][b], acc[3][b] };
                    *(int4*)&red[wv][b * 4] = q;
                }
            }
            __builtin_amdgcn_s_setprio(0);
        }
        // tail: 16 lanes/wave produce 4 rows x 4 batches (same-wave LDS dep)
        float hnew = 0.f;
        if (lane < 16) {
            int b = lane >> 2, rr = lane & 3;
            int row = wrow + rr;
            float a = (l > 0) ? (float)red[wv][lane] * SC : 0.f;
            float pre = a + xp[(size_t)(l * 4 + b) * NN + row];
            hnew = tanhf(pre);
            int q = (int)rintf(hnew * 127.f);
            hpk[wv][b][rr] = (unsigned char)(q & 0xff);
        }
        if (l < LLC - 1) {
            if (lane < 4) {
                int b = lane;
                unsigned d = *(const unsigned*)&hpk[wv][b][0];
                int hk = (row_base >> 2) + wv;
                int phys = ((hk >> 2) & 3) * 1024 + b * 256 + (hk >> 4) * 4 + (hk & 3);
                __hip_atomic_store(hq + (size_t)(l & 1) * 4096 + phys, d,
                                   __ATOMIC_RELAXED, __HIP_MEMORY_SCOPE_AGENT);
            }
            // ---- all-relaxed grid barrier (round-2 exact form) ----
            __syncthreads();                   // s_waitcnt vmcnt(0): h at coherence pt
            if (t == 0) {
                int g = blk & 7;
                int old = __hip_atomic_fetch_add(&bar[g * 32], 1, __ATOMIC_RELAXED,
                                                 __HIP_MEMORY_SCOPE_AGENT);
                if ((old & 31) == 31)
                    __hip_atomic_fetch_add(&bar[256], 1, __ATOMIC_RELAXED,
                                           __HIP_MEMORY_SCOPE_AGENT);
                int target = 8 * (l + 1);
                while (__hip_atomic_load(&bar[256], __ATOMIC_RELAXED,
                                         __HIP_MEMORY_SCOPE_AGENT) < target)
                    __builtin_amdgcn_s_sleep(2);
            }
            __syncthreads();
        } else {
            // ---- final step: fused k_out (g1 ready long ago; instant poll) ----
            if (t == 0) {
                while (__hip_atomic_load(&bar[352], __ATOMIC_RELAXED,
                                         __HIP_MEMORY_SCOPE_AGENT) < 512)
                    __builtin_amdgcn_s_sleep(2);
            }
            __syncthreads();
            if (lane < 16) {
                int b = lane >> 2, rr = lane & 3;
                int row = wrow + rr;
                float ge = 0.5f * hnew * (1.f + erff(hnew * 0.70710678118f));
                size_t gb = ((size_t)b * NN + row) * 10;
#pragma unroll
                for (int k = 0; k < 10; ++k) {
                    float gv = __hip_atomic_load(g1 + gb + k, __ATOMIC_RELAXED,
                                                 __HIP_MEMORY_SCOPE_AGENT);
                    out[gb + k] = 1.f / (1.f + __expf(-gv * ge));
                }
            }
        }
    }
}

extern "C" void kernel_launch(void* const* d_in, const int* in_sizes, int n_in,
                              void* d_out, int out_size, void* d_ws, size_t ws_size,
                              hipStream_t stream) {
    const int*   phi1_idx = (const int*)d_in[0];
    const float* phi1_val = (const float*)d_in[1];
    const int*   inv1_idx = (const int*)d_in[2];
    const float* inv1_val = (const float*)d_in[3];
    const int*   phi2_idx = (const int*)d_in[4];
    const float* phi2_val = (const float*)d_in[5];
    const int*   inv2_idx = (const int*)d_in[6];
    const float* inv2_val = (const float*)d_in[7];
    const float* fea      = (const float*)d_in[8];
    const int*   joblst   = (const int*)d_in[9];
    const float* W1       = (const float*)d_in[10];
    const float* d1       = (const float*)d_in[11];
    const float* W2       = (const float*)d_in[12];
    const float* d2       = (const float*)d_in[13];
    const float* W_ih     = (const float*)d_in[14];
    const float* W_hh     = (const float*)d_in[15];
    const float* b_ih     = (const float*)d_in[16];
    const float* b_hh     = (const float*)d_in[17];
    const float* dense_W  = (const float*)d_in[18];
    const float* dense_b  = (const float*)d_in[19];
    const float* item_emb = (const float*)d_in[20];

    float* ws = (float*)d_ws;                       // slot = 4B
    unsigned short* filt1 = (unsigned short*)ws;            // 1,048,576 slots
    unsigned short* filt2 = (unsigned short*)(ws + 1048576);
    unsigned short* y1    = (unsigned short*)(ws + 2097152);
    unsigned short* y2    = (unsigned short*)(ws + 3145728);
    float* g1   = ws + 4194304;                     // 163,840 slots
    float* xp   = ws + 6291456;                     // 819,200
    unsigned* hq  = (unsigned*)(ws + 7127040);      // 8,192 (2 x 4096 dwords)
    int*   rowptr = (int*)(ws + 11395072);          // 65,552
    int*   cursor = (int*)(ws + 11460624);          // 65,536
    unsigned* ep  = (unsigned*)(ws + 11526160);     // 1,048,576 (packed col|val)
    int*   bar    = (int*)(ws + 12574736);          // 512 ints (all barrier counters)

    hipMemsetAsync(bar, 0, 2048, stream);

    // Fused prep (barrier-free block-range concat): hist+scan | xproj | filt.
    k_prep<<<656, 256, 0, stream>>>(inv1_idx, phi1_idx, inv2_idx, phi2_idx,
                                    fea, W1, W2, item_emb, joblst,
                                    W_ih, b_ih, b_hh,
                                    rowptr, cursor, filt1, filt2, xp);

    k_scatter<<<4096, 256, 0, stream>>>(inv1_idx, phi1_idx, inv2_idx, phi2_idx,
                                        inv1_val, phi1_val, inv2_val, phi2_val,
                                        d1, d2, cursor, ep);

    // RNN (0..255) || workers (256..767); final RNN step emits out directly.
    k_mega<<<768, 256, 0, stream>>>(W_hh, xp, hq, bar,
                                    rowptr, ep, filt1, filt2, y1, y2,
                                    dense_W, dense_b, g1, (float*)d_out);
}